// Round 4
// baseline (1499.118 us; speedup 1.0000x reference)
//
#include <hip/hip_runtime.h>
#include <hip/hip_fp16.h>
#include <math.h>

// ---------------------------------------------------------------------------
// NetGlobGATFix. R3: aggregate-then-project restructure.
//   out[n,:] = selu( (1/H) Σ_h zinv[n,h] (Σ_e p_e hin[src_e,:]) @ W_h + b )
//   - gat_gather gathers hin fp16 rows (K ch) instead of hmid (H*C ch): 8-16x
//     fewer gather bytes; hin_f16 <= 5 MB (L2/L3 resident).
//   - es/ed = hin @ (W a_s) directly (tiny fp32 kernel, no hmid).
//   - One GEMM g @ W_stack fuses projection + head-mean + bias+selu+boundary.
//   - GEMM: split-bf16 3-MFMA core (A fp16 g, B fp32 W_stack).
// ---------------------------------------------------------------------------

#define DEVFN static __device__ __forceinline__

typedef __attribute__((ext_vector_type(8))) short short8;
typedef __attribute__((ext_vector_type(4))) float f32x4;

DEVFN float selu_f(float v) {
    const float scale = 1.0507009873554805f;
    const float alpha = 1.6732632423543772f;
    return v > 0.f ? scale * v : scale * alpha * (expf(v) - 1.f);
}

DEVFN float lrelu02(float v) { return v > 0.f ? v : 0.2f * v; }

// truncation split: hi = trunc_bf16(a); lo = trunc_bf16(a - hi)
DEVFN void split_bf16(float a, unsigned short& hi, unsigned short& lo) {
    unsigned u = __float_as_uint(a);
    hi = (unsigned short)(u >> 16);
    float hf = __uint_as_float(u & 0xFFFF0000u);
    float l = a - hf;
    lo = (unsigned short)(__float_as_uint(l) >> 16);
}

// ---------------- CNN ----------------
__global__ void conv3x3_selu(const float* __restrict__ in, const float* __restrict__ w,
                             const float* __restrict__ b, float* __restrict__ out,
                             int Cin, int Cout) {
    int t = blockIdx.x * blockDim.x + threadIdx.x;
    if (t >= Cout * 4096) return;
    int pix = t & 4095;
    int co  = t >> 12;
    int y = pix >> 6, x = pix & 63;
    float acc = b[co];
    for (int ci = 0; ci < Cin; ++ci) {
        const float* ip = in + ci * 4096;
        const float* wp = w + (co * Cin + ci) * 9;
#pragma unroll
        for (int ky = 0; ky < 3; ++ky) {
            int yy = y + ky - 1;
            if (yy < 0 || yy > 63) continue;
#pragma unroll
            for (int kx = 0; kx < 3; ++kx) {
                int xx = x + kx - 1;
                if (xx < 0 || xx > 63) continue;
                acc += ip[yy * 64 + xx] * wp[ky * 3 + kx];
            }
        }
    }
    out[t] = selu_f(acc);
}

__global__ void avgpool_c(const float* __restrict__ in, float* __restrict__ gfeat) {
    int c = blockIdx.x;            // 24 blocks
    int t = threadIdx.x;           // 256 threads
    float s = 0.f;
    for (int i = t; i < 4096; i += 256) s += in[c * 4096 + i];
#pragma unroll
    for (int off = 32; off >= 1; off >>= 1) s += __shfl_xor(s, off);
    __shared__ float red[4];
    int wave = t >> 6, lane = t & 63;
    if (lane == 0) red[wave] = s;
    __syncthreads();
    if (t == 0) gfeat[c] = (red[0] + red[1] + red[2] + red[3]) * (1.f / 4096.f);
}

// ---------------- node feature init (padded to 40 ch) + masks ---------------
__global__ void build_h0(const float* __restrict__ x, const float* __restrict__ gfeat,
                         float* __restrict__ h0, __half* __restrict__ h0f,
                         unsigned* __restrict__ masks, int N) {
    int n = blockIdx.x * blockDim.x + threadIdx.x;
    if (n >= N) return;
    float x0 = x[n * 10 + 0], x1 = x[n * 10 + 1];
    unsigned mk = (x0 == 1.f ? 1u : 0u) | (x0 == 0.f ? 2u : 0u) |
                  (x1 == 0.f ? 4u : 0u) | (x1 == 1.f ? 8u : 0u);
    masks[n] = mk;
    float* hp = h0 + (size_t)n * 40;
    __half* hq = h0f + (size_t)n * 40;
#pragma unroll
    for (int j = 0; j < 40; ++j) {
        float v = (j < 24) ? gfeat[j] : (j < 34 ? x[n * 10 + (j - 24)] : 0.f);
        hp[j] = v;
        hq[j] = __float2half(v);
    }
}

// ---------------- CSR build ----------------
__global__ void count_dst(const int* __restrict__ ei, int* __restrict__ cnt, int E, int N) {
    int t = blockIdx.x * blockDim.x + threadIdx.x;
    if (t >= E + N) return;
    int dst = (t < E) ? ei[E + t] : (t - E);
    atomicAdd(&cnt[dst], 1);
}

__global__ void exscan_single(const int* __restrict__ cnt, int* __restrict__ indptr, int n) {
    __shared__ int sdata[256];
    __shared__ int run_s;
    int tid = threadIdx.x;
    if (tid == 0) { run_s = 0; indptr[0] = 0; }
    __syncthreads();
    for (int base = 0; base < n; base += 256) {
        int i = base + tid;
        int v = (i < n) ? cnt[i] : 0;
        sdata[tid] = v;
        __syncthreads();
        for (int off = 1; off < 256; off <<= 1) {
            int tmp = (tid >= off) ? sdata[tid - off] : 0;
            __syncthreads();
            sdata[tid] += tmp;
            __syncthreads();
        }
        if (i < n) indptr[i + 1] = run_s + sdata[tid];
        __syncthreads();
        if (tid == 0) run_s += sdata[255];
        __syncthreads();
    }
}

__global__ void copy_int(const int* __restrict__ a, int* __restrict__ b, int n) {
    int t = blockIdx.x * blockDim.x + threadIdx.x;
    if (t < n) b[t] = a[t];
}

__global__ void scatter_edges(const int* __restrict__ ei, int* __restrict__ cursor,
                              int* __restrict__ col, int E, int N) {
    int t = blockIdx.x * blockDim.x + threadIdx.x;
    if (t >= E + N) return;
    int src, dst;
    if (t < E) { src = ei[t]; dst = ei[E + t]; }
    else       { src = dst = t - E; }
    int pos = atomicAdd(&cursor[dst], 1);
    col[pos] = src;
}

// ---------------- weight prep ----------------------------------------------
// wesed[k, o] (o<H: a_s, o>=H: a_d): Sum_c W[k, h*C+c] * a[h*C+c]; 0 for k>=K
__global__ void build_wesed(const float* __restrict__ W, const float* __restrict__ as,
                            const float* __restrict__ ad, float* __restrict__ wesed,
                            int K, int Kp, int H, int C) {
    int H2 = 2 * H;
    int t = blockIdx.x * blockDim.x + threadIdx.x;
    if (t >= Kp * H2) return;
    int k = t / H2, o = t - k * H2;
    float s = 0.f;
    if (k < K) {
        int h = (o < H) ? o : o - H;
        const float* av = ((o < H) ? as : ad) + h * C;
        const float* wp = W + (size_t)k * (H * C) + h * C;
        for (int c = 0; c < C; ++c) s += wp[c] * av[c];
    }
    wesed[t] = s;
}

// wstack[(h*Kp+k)*C + c] = W[k, h*C+c], 0-padded rows for k>=K
__global__ void build_wstack(const float* __restrict__ W, float* __restrict__ ws,
                             int K, int Kp, int H, int C) {
    int t = blockIdx.x * blockDim.x + threadIdx.x;
    if (t >= H * Kp * C) return;
    int c = t % C;
    int r = t / C;
    int h = r / Kp, k = r - h * Kp;
    ws[t] = (k < K) ? W[(size_t)k * (H * C) + h * C + c] : 0.f;
}

// ---------------- es/ed: esed[n, o] = hin[n,:] @ wesed[:,o], o < 2H ---------
__global__ void esed_kernel(const float* __restrict__ hin, const float* __restrict__ wesed,
                            float* __restrict__ esed, int N, int Kp, int H2) {
    int t = blockIdx.x * blockDim.x + threadIdx.x;
    if (t >= N * H2) return;
    int n = t / H2, o = t - n * H2;
    const float* hp = hin + (size_t)n * Kp;
    float s = 0.f;
    for (int k = 0; k < Kp; ++k) s += hp[k] * wesed[k * H2 + o];
    esed[t] = s;
}

// ---------------- attention: max + per-edge numerators + (1/H)/z ------------
__global__ void attn_kernel(const float* __restrict__ esed,
                            const int* __restrict__ indptr, const int* __restrict__ col,
                            float* __restrict__ palpha, float* __restrict__ zinv,
                            int N, int H) {
    int t = blockIdx.x * blockDim.x + threadIdx.x;
    if (t >= N * H) return;
    int n = t / H, h = t - n * H;
    int H2 = 2 * H;
    float edv = esed[n * H2 + H + h];
    int beg = indptr[n], end = indptr[n + 1];
    float mv = -3.4e38f;
    for (int i = beg; i < end; ++i) {
        float e = lrelu02(esed[col[i] * H2 + h] + edv);
        palpha[(size_t)i * H + h] = e;
        mv = fmaxf(mv, e);
    }
    float z = 0.f;
    for (int i = beg; i < end; ++i) {
        float p = expf(palpha[(size_t)i * H + h] - mv);
        palpha[(size_t)i * H + h] = p;
        z += p;
    }
    zinv[t] = (1.f / H) / (z + 1e-16f);
}

// ---------------- gather: g[n, h*KP+k] = zinv * Sum_e p * hin16[src, k] -----
template <int H, int KP, int NPB>
__global__ __launch_bounds__(NPB * KP / 2) void gat_gather(
        const __half* __restrict__ hinf, const float* __restrict__ palpha,
        const float* __restrict__ zinv, const int* __restrict__ indptr,
        const int* __restrict__ col, __half* __restrict__ g, int N) {
    const int TPN = KP / 2;
    int sub = threadIdx.x / TPN;
    int j   = threadIdx.x % TPN;
    int n = blockIdx.x * NPB + sub;
    if (n >= N) return;
    int c0 = j * 2;
    float acc[H][2];
#pragma unroll
    for (int h = 0; h < H; ++h) { acc[h][0] = 0.f; acc[h][1] = 0.f; }
    int beg = indptr[n], end = indptr[n + 1];
    for (int i = beg; i < end; ++i) {
        int src = col[i];
        __half2 hv = *(const __half2*)(hinf + (size_t)src * KP + c0);
        float2 f = __half22float2(hv);
        const float* ap = palpha + (size_t)i * H;
#pragma unroll
        for (int h = 0; h < H; ++h) {
            float a = ap[h];
            acc[h][0] += a * f.x;
            acc[h][1] += a * f.y;
        }
    }
    __half* gp = g + (size_t)n * (H * KP) + c0;
#pragma unroll
    for (int h = 0; h < H; ++h) {
        float zf = zinv[n * H + h];
        *(__half2*)(gp + h * KP) = __floats2half2_rn(acc[h][0] * zf, acc[h][1] * zf);
    }
}

// ---------------- GEMM: O = selu(g @ Wstack + bias), boundary fix, dual write
// A fp16 [N x K], B fp32 [K x M], K % 32 == 0, M % 64 == 0.
#define LDP 40
__global__ __launch_bounds__(256) void gemm_mfma(const __half* __restrict__ A,
                                                 const float* __restrict__ B,
                                                 const float* __restrict__ bias,
                                                 const unsigned* __restrict__ masks,
                                                 float* __restrict__ Of32,
                                                 __half* __restrict__ Of16,
                                                 int N, int K, int M) {
    __shared__ __attribute__((aligned(16))) unsigned short As_hi[64 * LDP];
    __shared__ __attribute__((aligned(16))) unsigned short As_lo[64 * LDP];
    __shared__ __attribute__((aligned(16))) unsigned short Bs_hi[64 * LDP];
    __shared__ __attribute__((aligned(16))) unsigned short Bs_lo[64 * LDP];

    int tid  = threadIdx.x;
    int wave = tid >> 6;
    int lane = tid & 63;
    int ln16 = lane & 15;
    int koff = (lane >> 4) * 8;
    int row0 = blockIdx.x * 64;
    int col0 = blockIdx.y * 64;

    f32x4 acc[4];
#pragma unroll
    for (int j = 0; j < 4; ++j) acc[j] = (f32x4){0.f, 0.f, 0.f, 0.f};

    for (int k0 = 0; k0 < K; k0 += 32) {
        for (int idx = tid; idx < 64 * 32; idx += 256) {
            int k = idx & 31, r = idx >> 5;
            int gr = row0 + r;
            float a = (gr < N) ? __half2float(A[(size_t)gr * K + k0 + k]) : 0.f;
            unsigned short h, l;
            split_bf16(a, h, l);
            As_hi[r * LDP + k] = h;
            As_lo[r * LDP + k] = l;
        }
        for (int idx = tid; idx < 32 * 64; idx += 256) {
            int n = idx & 63, k = idx >> 6;
            float b = B[(size_t)(k0 + k) * M + col0 + n];
            unsigned short h, l;
            split_bf16(b, h, l);
            Bs_hi[n * LDP + k] = h;
            Bs_lo[n * LDP + k] = l;
        }
        __syncthreads();

        int am = wave * 16 + ln16;
        short8 ah = *(const short8*)&As_hi[am * LDP + koff];
        short8 al = *(const short8*)&As_lo[am * LDP + koff];
#pragma unroll
        for (int j = 0; j < 4; ++j) {
            int bn = j * 16 + ln16;
            short8 bh = *(const short8*)&Bs_hi[bn * LDP + koff];
            short8 bl = *(const short8*)&Bs_lo[bn * LDP + koff];
            acc[j] = __builtin_amdgcn_mfma_f32_16x16x32_bf16(ah, bh, acc[j], 0, 0, 0);
            acc[j] = __builtin_amdgcn_mfma_f32_16x16x32_bf16(ah, bl, acc[j], 0, 0, 0);
            acc[j] = __builtin_amdgcn_mfma_f32_16x16x32_bf16(al, bh, acc[j], 0, 0, 0);
        }
        __syncthreads();
    }

    // C/D layout: col = lane&15, row = (lane>>4)*4 + reg
#pragma unroll
    for (int j = 0; j < 4; ++j) {
        int cc = col0 + j * 16 + ln16;
#pragma unroll
        for (int r = 0; r < 4; ++r) {
            int rr = row0 + wave * 16 + (lane >> 4) * 4 + r;
            if (rr >= N) continue;
            float v = acc[j][r] + bias[cc];
            v = selu_f(v);
            if (cc < 2) {
                unsigned mk = masks[rr];
                if (cc == 0) { if (mk & 2u) v = 0.f; else if (mk & 1u) v = 1.f; }
                else         { if (mk & 8u) v = 1.f; else if (mk & 4u) v = 0.f; }
            }
            Of32[(size_t)rr * M + cc] = v;
            Of16[(size_t)rr * M + cc] = __float2half(v);
        }
    }
}

// ---------------- final layer (C=2): out = bfix(x + selu(g @ W5s + b5)) -----
__global__ __launch_bounds__(256) void final5_kernel(const __half* __restrict__ g,
                                                     const float* __restrict__ W5,
                                                     const float* __restrict__ b5,
                                                     const unsigned* __restrict__ masks,
                                                     const float* __restrict__ x,
                                                     float* __restrict__ out,
                                                     int N, int KA) {
    int wave = threadIdx.x >> 6, lane = threadIdx.x & 63;
    int n = blockIdx.x * 4 + wave;
    if (n >= N) return;
    float a0 = 0.f, a1 = 0.f;
    const __half* gp = g + (size_t)n * KA;
    for (int k = lane * 2; k < KA; k += 128) {
        float2 f = __half22float2(*(const __half2*)(gp + k));
        float4 w = *(const float4*)(W5 + (size_t)k * 2);
        a0 += f.x * w.x + f.y * w.z;
        a1 += f.x * w.y + f.y * w.w;
    }
#pragma unroll
    for (int off = 32; off >= 1; off >>= 1) {
        a0 += __shfl_xor(a0, off);
        a1 += __shfl_xor(a1, off);
    }
    if (lane == 0) {
        unsigned mk = masks[n];
        float v0 = x[n * 10 + 0] + selu_f(a0 + b5[0]);
        float v1 = x[n * 10 + 1] + selu_f(a1 + b5[1]);
        if (mk & 2u) v0 = 0.f; else if (mk & 1u) v0 = 1.f;
        if (mk & 8u) v1 = 1.f; else if (mk & 4u) v1 = 0.f;
        out[n * 2 + 0] = v0;
        out[n * 2 + 1] = v1;
    }
}

// ---------------------------------------------------------------------------
extern "C" void kernel_launch(void* const* d_in, const int* in_sizes, int n_in,
                              void* d_out, int out_size, void* d_ws, size_t ws_size,
                              hipStream_t stream) {
    const float* x   = (const float*)d_in[0];
    const int*   ei  = (const int*)d_in[1];
    const float* cf  = (const float*)d_in[2];
    const float* cw[4] = {(const float*)d_in[3], (const float*)d_in[5],
                          (const float*)d_in[7], (const float*)d_in[9]};
    const float* cb[4] = {(const float*)d_in[4], (const float*)d_in[6],
                          (const float*)d_in[8], (const float*)d_in[10]};
    const float* gw[5], *gas[5], *gad[5], *gb[5];
    for (int i = 0; i < 5; ++i) {
        gw[i]  = (const float*)d_in[11 + 4 * i];
        gas[i] = (const float*)d_in[12 + 4 * i];
        gad[i] = (const float*)d_in[13 + 4 * i];
        gb[i]  = (const float*)d_in[14 + 4 * i];
    }
    const int N = in_sizes[0] / 10;        // 10000
    const int E = in_sizes[1] / 2;         // 160000
    const int EN = E + N;

    // ---- workspace carve-up ----
    char* base = (char*)d_ws;
    size_t off = 0;
    auto alloc = [&](size_t bytes) -> char* {
        char* p = base + off;
        off = (off + bytes + 255) & ~(size_t)255;
        return p;
    };
    float* c1    = (float*)alloc(16 * 4096 * 4);
    float* c2    = (float*)alloc(32 * 4096 * 4);
    float* c3    = (float*)alloc(64 * 4096 * 4);
    float* c4    = (float*)alloc(24 * 4096 * 4);
    float* gfeat = (float*)alloc(24 * 4);
    float* hA    = (float*)alloc((size_t)N * 256 * 4);   // fp32 ping
    float* hB    = (float*)alloc((size_t)N * 256 * 4);   // fp32 pong
    __half* hA16 = (__half*)alloc((size_t)N * 256 * 2);
    __half* hB16 = (__half*)alloc((size_t)N * 256 * 2);
    __half* g    = (__half*)alloc((size_t)N * 2048 * 2); // gathered per-head hin
    float* esed  = (float*)alloc((size_t)N * 32 * 4);
    float* zinv  = (float*)alloc((size_t)N * 16 * 4);
    float* palpha= (float*)alloc((size_t)EN * 16 * 4);
    float* wesed = (float*)alloc(256 * 32 * 4);
    float* wstack= (float*)alloc((size_t)2048 * 256 * 4); // 2 MB, covers max H*Kp x C
    unsigned* masks = (unsigned*)alloc((size_t)N * 4);
    int* cnt    = (int*)alloc((size_t)N * 4);
    int* indptr = (int*)alloc((size_t)(N + 1) * 4);
    int* cursor = (int*)alloc((size_t)N * 4);
    int* col    = (int*)alloc((size_t)EN * 4);
    (void)ws_size; // ~92 MB

    // ---- CNN ----
    conv3x3_selu<<<(16 * 4096 + 255) / 256, 256, 0, stream>>>(cf, cw[0], cb[0], c1, 4, 16);
    conv3x3_selu<<<(32 * 4096 + 255) / 256, 256, 0, stream>>>(c1, cw[1], cb[1], c2, 16, 32);
    conv3x3_selu<<<(64 * 4096 + 255) / 256, 256, 0, stream>>>(c2, cw[2], cb[2], c3, 32, 64);
    conv3x3_selu<<<(24 * 4096 + 255) / 256, 256, 0, stream>>>(c3, cw[3], cb[3], c4, 64, 24);
    avgpool_c<<<24, 256, 0, stream>>>(c4, gfeat);

    // ---- h0 (padded to 40) + masks ----
    build_h0<<<(N + 255) / 256, 256, 0, stream>>>(x, gfeat, hA, hA16, masks, N);

    // ---- CSR by dst (incl self loops) ----
    hipMemsetAsync(cnt, 0, (size_t)N * 4, stream);
    count_dst<<<(EN + 255) / 256, 256, 0, stream>>>(ei, cnt, E, N);
    exscan_single<<<1, 256, 0, stream>>>(cnt, indptr, N);
    copy_int<<<(N + 255) / 256, 256, 0, stream>>>(indptr, cursor, N);
    scatter_edges<<<(EN + 255) / 256, 256, 0, stream>>>(ei, cursor, col, E, N);

    // ---- GAT layers ----
    const int Ko[5] = {34, 64, 128, 256, 128};   // true input dims
    const int Kp[5] = {40, 64, 128, 256, 128};   // padded input dims
    const int Hs[5] = {8, 16, 8, 8, 16};
    const int Cs[5] = {64, 128, 256, 128, 2};

    const float* hin   = hA;   const __half* hin16 = hA16;
    float* hout[4]     = {hB, hA, hB, hA};
    __half* hout16[4]  = {hB16, hA16, hB16, hA16};

    for (int lyr = 0; lyr < 5; ++lyr) {
        int K = Ko[lyr], KP = Kp[lyr], H = Hs[lyr], C = Cs[lyr];
        int KA = H * KP;
        build_wesed<<<(KP * 2 * H + 255) / 256, 256, 0, stream>>>(gw[lyr], gas[lyr], gad[lyr],
                                                                  wesed, K, KP, H, C);
        build_wstack<<<(KA * C + 255) / 256, 256, 0, stream>>>(gw[lyr], wstack, K, KP, H, C);
        esed_kernel<<<(N * 2 * H + 255) / 256, 256, 0, stream>>>(hin, wesed, esed, N, KP, 2 * H);
        attn_kernel<<<(N * H + 255) / 256, 256, 0, stream>>>(esed, indptr, col, palpha, zinv, N, H);
        if (lyr == 0)
            gat_gather<8, 40, 12><<<(N + 11) / 12, 240, 0, stream>>>(hin16, palpha, zinv, indptr, col, g, N);
        else if (lyr == 1)
            gat_gather<16, 64, 8><<<(N + 7) / 8, 256, 0, stream>>>(hin16, palpha, zinv, indptr, col, g, N);
        else if (lyr == 2)
            gat_gather<8, 128, 4><<<(N + 3) / 4, 256, 0, stream>>>(hin16, palpha, zinv, indptr, col, g, N);
        else if (lyr == 3)
            gat_gather<8, 256, 2><<<(N + 1) / 2, 256, 0, stream>>>(hin16, palpha, zinv, indptr, col, g, N);
        else
            gat_gather<16, 128, 4><<<(N + 3) / 4, 256, 0, stream>>>(hin16, palpha, zinv, indptr, col, g, N);

        if (lyr < 4) {
            dim3 ggrid((N + 63) / 64, C / 64);
            gemm_mfma<<<ggrid, 256, 0, stream>>>(g, wstack, gb[lyr], masks,
                                                 hout[lyr], hout16[lyr], N, KA, C);
            hin = hout[lyr];
            hin16 = hout16[lyr];
        } else {
            final5_kernel<<<(N + 3) / 4, 256, 0, stream>>>(g, wstack, gb[4], masks, x,
                                                           (float*)d_out, N, KA);
        }
    }
}

// Round 5
// 1133.187 us; speedup vs baseline: 1.3229x; 1.3229x over previous
//
#include <hip/hip_runtime.h>
#include <hip/hip_fp16.h>
#include <math.h>

// ---------------------------------------------------------------------------
// NetGlobGATFix. R5: keep R4's aggregate-then-project dataflow (gather is
// cheap now) but replace the LDS-staged GEMM with a no-LDS wave-granular
// MFMA GEMM suited to narrow-M shapes:
//   - grid (N/16, M/64), 64 threads/block, one 16x64 tile per wave
//   - B pre-transposed + split-bf16 into [m][k] hi/lo planes (L2-resident);
//     lanes load aligned short8 fragments directly from cache
//   - A (fp16 g) loaded dwordx4 + split in-register
//   - no __syncthreads, no LDS, no bank conflicts
//   - hout fp16 only (esed reads fp16; fp32 ping-pong dropped)
// ---------------------------------------------------------------------------

#define DEVFN static __device__ __forceinline__

typedef __attribute__((ext_vector_type(8))) short short8;
typedef __attribute__((ext_vector_type(4))) float f32x4;

DEVFN float selu_f(float v) {
    const float scale = 1.0507009873554805f;
    const float alpha = 1.6732632423543772f;
    return v > 0.f ? scale * v : scale * alpha * (expf(v) - 1.f);
}

DEVFN float lrelu02(float v) { return v > 0.f ? v : 0.2f * v; }

// truncation split: hi = trunc_bf16(a); lo = trunc_bf16(a - hi)
DEVFN void split_bf16(float a, unsigned short& hi, unsigned short& lo) {
    unsigned u = __float_as_uint(a);
    hi = (unsigned short)(u >> 16);
    float hf = __uint_as_float(u & 0xFFFF0000u);
    float l = a - hf;
    lo = (unsigned short)(__float_as_uint(l) >> 16);
}

// ---------------- CNN ----------------
__global__ void conv3x3_selu(const float* __restrict__ in, const float* __restrict__ w,
                             const float* __restrict__ b, float* __restrict__ out,
                             int Cin, int Cout) {
    int t = blockIdx.x * blockDim.x + threadIdx.x;
    if (t >= Cout * 4096) return;
    int pix = t & 4095;
    int co  = t >> 12;
    int y = pix >> 6, x = pix & 63;
    float acc = b[co];
    for (int ci = 0; ci < Cin; ++ci) {
        const float* ip = in + ci * 4096;
        const float* wp = w + (co * Cin + ci) * 9;
#pragma unroll
        for (int ky = 0; ky < 3; ++ky) {
            int yy = y + ky - 1;
            if (yy < 0 || yy > 63) continue;
#pragma unroll
            for (int kx = 0; kx < 3; ++kx) {
                int xx = x + kx - 1;
                if (xx < 0 || xx > 63) continue;
                acc += ip[yy * 64 + xx] * wp[ky * 3 + kx];
            }
        }
    }
    out[t] = selu_f(acc);
}

__global__ void avgpool_c(const float* __restrict__ in, float* __restrict__ gfeat) {
    int c = blockIdx.x;            // 24 blocks
    int t = threadIdx.x;           // 256 threads
    float s = 0.f;
    for (int i = t; i < 4096; i += 256) s += in[c * 4096 + i];
#pragma unroll
    for (int off = 32; off >= 1; off >>= 1) s += __shfl_xor(s, off);
    __shared__ float red[4];
    int wave = t >> 6, lane = t & 63;
    if (lane == 0) red[wave] = s;
    __syncthreads();
    if (t == 0) gfeat[c] = (red[0] + red[1] + red[2] + red[3]) * (1.f / 4096.f);
}

// ---------------- node feature init (padded to 40 ch, fp16) + masks ---------
__global__ void build_h0(const float* __restrict__ x, const float* __restrict__ gfeat,
                         __half* __restrict__ h0f, unsigned* __restrict__ masks, int N) {
    int n = blockIdx.x * blockDim.x + threadIdx.x;
    if (n >= N) return;
    float x0 = x[n * 10 + 0], x1 = x[n * 10 + 1];
    unsigned mk = (x0 == 1.f ? 1u : 0u) | (x0 == 0.f ? 2u : 0u) |
                  (x1 == 0.f ? 4u : 0u) | (x1 == 1.f ? 8u : 0u);
    masks[n] = mk;
    __half* hq = h0f + (size_t)n * 40;
#pragma unroll
    for (int j = 0; j < 40; ++j) {
        float v = (j < 24) ? gfeat[j] : (j < 34 ? x[n * 10 + (j - 24)] : 0.f);
        hq[j] = __float2half(v);
    }
}

// ---------------- CSR build ----------------
__global__ void count_dst(const int* __restrict__ ei, int* __restrict__ cnt, int E, int N) {
    int t = blockIdx.x * blockDim.x + threadIdx.x;
    if (t >= E + N) return;
    int dst = (t < E) ? ei[E + t] : (t - E);
    atomicAdd(&cnt[dst], 1);
}

__global__ void exscan_single(const int* __restrict__ cnt, int* __restrict__ indptr, int n) {
    __shared__ int sdata[256];
    __shared__ int run_s;
    int tid = threadIdx.x;
    if (tid == 0) { run_s = 0; indptr[0] = 0; }
    __syncthreads();
    for (int base = 0; base < n; base += 256) {
        int i = base + tid;
        int v = (i < n) ? cnt[i] : 0;
        sdata[tid] = v;
        __syncthreads();
        for (int off = 1; off < 256; off <<= 1) {
            int tmp = (tid >= off) ? sdata[tid - off] : 0;
            __syncthreads();
            sdata[tid] += tmp;
            __syncthreads();
        }
        if (i < n) indptr[i + 1] = run_s + sdata[tid];
        __syncthreads();
        if (tid == 0) run_s += sdata[255];
        __syncthreads();
    }
}

__global__ void copy_int(const int* __restrict__ a, int* __restrict__ b, int n) {
    int t = blockIdx.x * blockDim.x + threadIdx.x;
    if (t < n) b[t] = a[t];
}

__global__ void scatter_edges(const int* __restrict__ ei, int* __restrict__ cursor,
                              int* __restrict__ col, int E, int N) {
    int t = blockIdx.x * blockDim.x + threadIdx.x;
    if (t >= E + N) return;
    int src, dst;
    if (t < E) { src = ei[t]; dst = ei[E + t]; }
    else       { src = dst = t - E; }
    int pos = atomicAdd(&cursor[dst], 1);
    col[pos] = src;
}

// ---------------- weight prep ----------------------------------------------
// wesed[k, o] (o<H: a_s, o>=H: a_d): Sum_c W[k, h*C+c] * a[h*C+c]; 0 for k>=K
__global__ void build_wesed(const float* __restrict__ W, const float* __restrict__ as,
                            const float* __restrict__ ad, float* __restrict__ wesed,
                            int K, int Kp, int H, int C) {
    int H2 = 2 * H;
    int t = blockIdx.x * blockDim.x + threadIdx.x;
    if (t >= Kp * H2) return;
    int k = t / H2, o = t - k * H2;
    float s = 0.f;
    if (k < K) {
        int h = (o < H) ? o : o - H;
        const float* av = ((o < H) ? as : ad) + h * C;
        const float* wp = W + (size_t)k * (H * C) + h * C;
        for (int c = 0; c < C; ++c) s += wp[c] * av[c];
    }
    wesed[t] = s;
}

// Bt_hi/Bt_lo[m * KA + (h*Kp + k)] = split_bf16(W[k, h*C+m]), 0 pad for k>=K
__global__ void build_wtb(const float* __restrict__ W, unsigned short* __restrict__ bhi,
                          unsigned short* __restrict__ blo, int K, int Kp, int H, int C) {
    int KA = H * Kp;
    int t = blockIdx.x * blockDim.x + threadIdx.x;
    if (t >= C * KA) return;
    int ka = t % KA;
    int m  = t / KA;
    int h = ka / Kp, k = ka - h * Kp;
    float v = (k < K) ? W[(size_t)k * (H * C) + h * C + m] : 0.f;
    unsigned short hi, lo;
    split_bf16(v, hi, lo);
    bhi[t] = hi;
    blo[t] = lo;
}

// wstack[(h*Kp+k)*C + c] = W[k, h*C+c] (fp32; used for final layer C=2)
__global__ void build_wstack(const float* __restrict__ W, float* __restrict__ ws,
                             int K, int Kp, int H, int C) {
    int t = blockIdx.x * blockDim.x + threadIdx.x;
    if (t >= H * Kp * C) return;
    int c = t % C;
    int r = t / C;
    int h = r / Kp, k = r - h * Kp;
    ws[t] = (k < K) ? W[(size_t)k * (H * C) + h * C + c] : 0.f;
}

// ---------------- es/ed: esed[n, o] = hin16[n,:] @ wesed[:,o], o < 2H -------
__global__ void esed_kernel(const __half* __restrict__ hin, const float* __restrict__ wesed,
                            float* __restrict__ esed, int N, int Kp, int H2) {
    int t = blockIdx.x * blockDim.x + threadIdx.x;
    if (t >= N * H2) return;
    int n = t / H2, o = t - n * H2;
    const __half* hp = hin + (size_t)n * Kp;
    float s = 0.f;
    for (int k = 0; k < Kp; ++k) s += __half2float(hp[k]) * wesed[k * H2 + o];
    esed[t] = s;
}

// ---------------- attention: max + per-edge numerators + (1/H)/z ------------
__global__ void attn_kernel(const float* __restrict__ esed,
                            const int* __restrict__ indptr, const int* __restrict__ col,
                            float* __restrict__ palpha, float* __restrict__ zinv,
                            int N, int H) {
    int t = blockIdx.x * blockDim.x + threadIdx.x;
    if (t >= N * H) return;
    int n = t / H, h = t - n * H;
    int H2 = 2 * H;
    float edv = esed[n * H2 + H + h];
    int beg = indptr[n], end = indptr[n + 1];
    float mv = -3.4e38f;
    for (int i = beg; i < end; ++i) {
        float e = lrelu02(esed[col[i] * H2 + h] + edv);
        palpha[(size_t)i * H + h] = e;
        mv = fmaxf(mv, e);
    }
    float z = 0.f;
    for (int i = beg; i < end; ++i) {
        float p = expf(palpha[(size_t)i * H + h] - mv);
        palpha[(size_t)i * H + h] = p;
        z += p;
    }
    zinv[t] = (1.f / H) / (z + 1e-16f);
}

// ---------------- gather: g[n, h*KP+k] = zinv * Sum_e p * hin16[src, k] -----
template <int H, int KP, int NPB>
__global__ __launch_bounds__(NPB * KP / 2) void gat_gather(
        const __half* __restrict__ hinf, const float* __restrict__ palpha,
        const float* __restrict__ zinv, const int* __restrict__ indptr,
        const int* __restrict__ col, __half* __restrict__ g, int N) {
    const int TPN = KP / 2;
    int sub = threadIdx.x / TPN;
    int j   = threadIdx.x % TPN;
    int n = blockIdx.x * NPB + sub;
    if (n >= N) return;
    int c0 = j * 2;
    float acc[H][2];
#pragma unroll
    for (int h = 0; h < H; ++h) { acc[h][0] = 0.f; acc[h][1] = 0.f; }
    int beg = indptr[n], end = indptr[n + 1];
    for (int i = beg; i < end; ++i) {
        int src = col[i];
        __half2 hv = *(const __half2*)(hinf + (size_t)src * KP + c0);
        float2 f = __half22float2(hv);
        const float* ap = palpha + (size_t)i * H;
#pragma unroll
        for (int h = 0; h < H; ++h) {
            float a = ap[h];
            acc[h][0] += a * f.x;
            acc[h][1] += a * f.y;
        }
    }
    __half* gp = g + (size_t)n * (H * KP) + c0;
#pragma unroll
    for (int h = 0; h < H; ++h) {
        float zf = zinv[n * H + h];
        *(__half2*)(gp + h * KP) = __floats2half2_rn(acc[h][0] * zf, acc[h][1] * zf);
    }
}

// ---------------- no-LDS MFMA GEMM ------------------------------------------
// O16 = bfix(selu(A @ Bt^T + bias)); A fp16 [N x K], Bt hi/lo [M x K] planes.
// grid (N/16, M/64), 64 threads (1 wave). Tile: 16 rows x 64 cols.
// N % 16 == 0, K % 32 == 0, M % 64 == 0.
__global__ __launch_bounds__(64) void gemm16(const __half* __restrict__ A,
                                             const unsigned short* __restrict__ Bhi,
                                             const unsigned short* __restrict__ Blo,
                                             const float* __restrict__ bias,
                                             const unsigned* __restrict__ masks,
                                             __half* __restrict__ O16,
                                             int N, int K, int M) {
    int lane = threadIdx.x;
    int ln16 = lane & 15;
    int q    = lane >> 4;                 // 0..3 (k-octet)
    int row0 = blockIdx.x * 16;
    int col0 = blockIdx.y * 64;

    const __half* ap = A + (size_t)(row0 + ln16) * K + q * 8;
    const unsigned short* bhp = Bhi + (size_t)(col0 + ln16) * K + q * 8;
    const unsigned short* blp = Blo + (size_t)(col0 + ln16) * K + q * 8;

    f32x4 acc[4];
#pragma unroll
    for (int j = 0; j < 4; ++j) acc[j] = (f32x4){0.f, 0.f, 0.f, 0.f};

    for (int k0 = 0; k0 < K; k0 += 32) {
        // A fragment: 8 fp16 -> split-bf16 hi/lo in-register
        short8 araw = *(const short8*)(ap + k0);
        short8 ah, al;
#pragma unroll
        for (int i = 0; i < 8; ++i) {
            __half_raw hr;
            hr.x = (unsigned short)araw[i];
            float f = __half2float(*(const __half*)&hr);
            unsigned u = __float_as_uint(f);
            ah[i] = (short)(u >> 16);
            float lf = f - __uint_as_float(u & 0xFFFF0000u);
            al[i] = (short)(__float_as_uint(lf) >> 16);
        }
#pragma unroll
        for (int j = 0; j < 4; ++j) {
            short8 bh = *(const short8*)(bhp + (size_t)j * 16 * K + k0);
            short8 bl = *(const short8*)(blp + (size_t)j * 16 * K + k0);
            acc[j] = __builtin_amdgcn_mfma_f32_16x16x32_bf16(ah, bh, acc[j], 0, 0, 0);
            acc[j] = __builtin_amdgcn_mfma_f32_16x16x32_bf16(ah, bl, acc[j], 0, 0, 0);
            acc[j] = __builtin_amdgcn_mfma_f32_16x16x32_bf16(al, bh, acc[j], 0, 0, 0);
        }
    }

    // C/D layout: col = lane&15, row = (lane>>4)*4 + reg
#pragma unroll
    for (int j = 0; j < 4; ++j) {
        int cc = col0 + j * 16 + ln16;
        float bv = bias[cc];
#pragma unroll
        for (int r = 0; r < 4; ++r) {
            int rr = row0 + q * 4 + r;
            float v = selu_f(acc[j][r] + bv);
            if (cc < 2) {
                unsigned mk = masks[rr];
                if (cc == 0) { if (mk & 2u) v = 0.f; else if (mk & 1u) v = 1.f; }
                else         { if (mk & 8u) v = 1.f; else if (mk & 4u) v = 0.f; }
            }
            O16[(size_t)rr * M + cc] = __float2half(v);
        }
    }
}

// ---------------- final layer (C=2): out = bfix(x + selu(g @ W5s + b5)) -----
__global__ __launch_bounds__(256) void final5_kernel(const __half* __restrict__ g,
                                                     const float* __restrict__ W5,
                                                     const float* __restrict__ b5,
                                                     const unsigned* __restrict__ masks,
                                                     const float* __restrict__ x,
                                                     float* __restrict__ out,
                                                     int N, int KA) {
    int wave = threadIdx.x >> 6, lane = threadIdx.x & 63;
    int n = blockIdx.x * 4 + wave;
    if (n >= N) return;
    float a0 = 0.f, a1 = 0.f;
    const __half* gp = g + (size_t)n * KA;
    for (int k = lane * 2; k < KA; k += 128) {
        float2 f = __half22float2(*(const __half2*)(gp + k));
        float4 w = *(const float4*)(W5 + (size_t)k * 2);
        a0 += f.x * w.x + f.y * w.z;
        a1 += f.x * w.y + f.y * w.w;
    }
#pragma unroll
    for (int off = 32; off >= 1; off >>= 1) {
        a0 += __shfl_xor(a0, off);
        a1 += __shfl_xor(a1, off);
    }
    if (lane == 0) {
        unsigned mk = masks[n];
        float v0 = x[n * 10 + 0] + selu_f(a0 + b5[0]);
        float v1 = x[n * 10 + 1] + selu_f(a1 + b5[1]);
        if (mk & 2u) v0 = 0.f; else if (mk & 1u) v0 = 1.f;
        if (mk & 8u) v1 = 1.f; else if (mk & 4u) v1 = 0.f;
        out[n * 2 + 0] = v0;
        out[n * 2 + 1] = v1;
    }
}

// ---------------------------------------------------------------------------
extern "C" void kernel_launch(void* const* d_in, const int* in_sizes, int n_in,
                              void* d_out, int out_size, void* d_ws, size_t ws_size,
                              hipStream_t stream) {
    const float* x   = (const float*)d_in[0];
    const int*   ei  = (const int*)d_in[1];
    const float* cf  = (const float*)d_in[2];
    const float* cw[4] = {(const float*)d_in[3], (const float*)d_in[5],
                          (const float*)d_in[7], (const float*)d_in[9]};
    const float* cb[4] = {(const float*)d_in[4], (const float*)d_in[6],
                          (const float*)d_in[8], (const float*)d_in[10]};
    const float* gw[5], *gas[5], *gad[5], *gb[5];
    for (int i = 0; i < 5; ++i) {
        gw[i]  = (const float*)d_in[11 + 4 * i];
        gas[i] = (const float*)d_in[12 + 4 * i];
        gad[i] = (const float*)d_in[13 + 4 * i];
        gb[i]  = (const float*)d_in[14 + 4 * i];
    }
    const int N = in_sizes[0] / 10;        // 10000
    const int E = in_sizes[1] / 2;         // 160000
    const int EN = E + N;

    // ---- workspace carve-up ----
    char* base = (char*)d_ws;
    size_t off = 0;
    auto alloc = [&](size_t bytes) -> char* {
        char* p = base + off;
        off = (off + bytes + 255) & ~(size_t)255;
        return p;
    };
    float* c1    = (float*)alloc(16 * 4096 * 4);
    float* c2    = (float*)alloc(32 * 4096 * 4);
    float* c3    = (float*)alloc(64 * 4096 * 4);
    float* c4    = (float*)alloc(24 * 4096 * 4);
    float* gfeat = (float*)alloc(24 * 4);
    __half* hA16 = (__half*)alloc((size_t)N * 256 * 2);
    __half* hB16 = (__half*)alloc((size_t)N * 256 * 2);
    __half* g    = (__half*)alloc((size_t)N * 2048 * 2); // gathered per-head hin
    float* esed  = (float*)alloc((size_t)N * 32 * 4);
    float* zinv  = (float*)alloc((size_t)N * 16 * 4);
    float* palpha= (float*)alloc((size_t)EN * 16 * 4);
    float* wesed = (float*)alloc(256 * 32 * 4);
    float* wstack= (float*)alloc((size_t)2048 * 2 * 4);        // final layer W (fp32)
    unsigned short* bt_hi = (unsigned short*)alloc((size_t)262144 * 2); // max M*KA
    unsigned short* bt_lo = (unsigned short*)alloc((size_t)262144 * 2);
    unsigned* masks = (unsigned*)alloc((size_t)N * 4);
    int* cnt    = (int*)alloc((size_t)N * 4);
    int* indptr = (int*)alloc((size_t)(N + 1) * 4);
    int* cursor = (int*)alloc((size_t)N * 4);
    int* col    = (int*)alloc((size_t)EN * 4);
    (void)ws_size; // ~70 MB

    // ---- CNN ----
    conv3x3_selu<<<(16 * 4096 + 255) / 256, 256, 0, stream>>>(cf, cw[0], cb[0], c1, 4, 16);
    conv3x3_selu<<<(32 * 4096 + 255) / 256, 256, 0, stream>>>(c1, cw[1], cb[1], c2, 16, 32);
    conv3x3_selu<<<(64 * 4096 + 255) / 256, 256, 0, stream>>>(c2, cw[2], cb[2], c3, 32, 64);
    conv3x3_selu<<<(24 * 4096 + 255) / 256, 256, 0, stream>>>(c3, cw[3], cb[3], c4, 64, 24);
    avgpool_c<<<24, 256, 0, stream>>>(c4, gfeat);

    // ---- h0 (padded to 40, fp16) + masks ----
    build_h0<<<(N + 255) / 256, 256, 0, stream>>>(x, gfeat, hA16, masks, N);

    // ---- CSR by dst (incl self loops) ----
    hipMemsetAsync(cnt, 0, (size_t)N * 4, stream);
    count_dst<<<(EN + 255) / 256, 256, 0, stream>>>(ei, cnt, E, N);
    exscan_single<<<1, 256, 0, stream>>>(cnt, indptr, N);
    copy_int<<<(N + 255) / 256, 256, 0, stream>>>(indptr, cursor, N);
    scatter_edges<<<(EN + 255) / 256, 256, 0, stream>>>(ei, cursor, col, E, N);

    // ---- GAT layers ----
    const int Ko[5] = {34, 64, 128, 256, 128};   // true input dims
    const int Kp[5] = {40, 64, 128, 256, 128};   // padded input dims
    const int Hs[5] = {8, 16, 8, 8, 16};
    const int Cs[5] = {64, 128, 256, 128, 2};

    const __half* hin16 = hA16;
    __half* hout16[4]  = {hB16, hA16, hB16, hA16};

    for (int lyr = 0; lyr < 5; ++lyr) {
        int K = Ko[lyr], KP = Kp[lyr], H = Hs[lyr], C = Cs[lyr];
        int KA = H * KP;
        build_wesed<<<(KP * 2 * H + 255) / 256, 256, 0, stream>>>(gw[lyr], gas[lyr], gad[lyr],
                                                                  wesed, K, KP, H, C);
        esed_kernel<<<(N * 2 * H + 255) / 256, 256, 0, stream>>>(hin16, wesed, esed, N, KP, 2 * H);
        attn_kernel<<<(N * H + 255) / 256, 256, 0, stream>>>(esed, indptr, col, palpha, zinv, N, H);
        if (lyr == 0)
            gat_gather<8, 40, 12><<<(N + 11) / 12, 240, 0, stream>>>(hin16, palpha, zinv, indptr, col, g, N);
        else if (lyr == 1)
            gat_gather<16, 64, 8><<<(N + 7) / 8, 256, 0, stream>>>(hin16, palpha, zinv, indptr, col, g, N);
        else if (lyr == 2)
            gat_gather<8, 128, 4><<<(N + 3) / 4, 256, 0, stream>>>(hin16, palpha, zinv, indptr, col, g, N);
        else if (lyr == 3)
            gat_gather<8, 256, 2><<<(N + 1) / 2, 256, 0, stream>>>(hin16, palpha, zinv, indptr, col, g, N);
        else
            gat_gather<16, 128, 4><<<(N + 3) / 4, 256, 0, stream>>>(hin16, palpha, zinv, indptr, col, g, N);

        if (lyr < 4) {
            build_wtb<<<(C * KA + 255) / 256, 256, 0, stream>>>(gw[lyr], bt_hi, bt_lo, K, KP, H, C);
            dim3 ggrid(N / 16, C / 64);
            gemm16<<<ggrid, 64, 0, stream>>>(g, bt_hi, bt_lo, gb[lyr], masks,
                                             hout16[lyr], N, KA, C);
            hin16 = hout16[lyr];
        } else {
            build_wstack<<<(KA * 2 + 255) / 256, 256, 0, stream>>>(gw[4], wstack, K, KP, H, 2);
            final5_kernel<<<(N + 3) / 4, 256, 0, stream>>>(g, wstack, gb[4], masks, x,
                                                           (float*)d_out, N, KA);
        }
    }
}

// Round 6
// 1118.575 us; speedup vs baseline: 1.3402x; 1.0131x over previous
//
#include <hip/hip_runtime.h>
#include <hip/hip_fp16.h>
#include <math.h>

// ---------------------------------------------------------------------------
// NetGlobGATFix. R6: software-pipelined no-LDS MFMA GEMM.
//   - gemm16: block = N-tile(16) x full M; NW waves (one 16x64 tile each);
//     A prefetched 4 chunks deep in rotating regs (static unroll over 128-k
//     superblocks); B (L2-resident hi/lo bf16 planes) loaded per chunk.
//   - K padded to multiples of 128 (layer1: 48*8=384).
//   - palpha stored fp16, written once (attn recomputes e in pass 2).
// ---------------------------------------------------------------------------

#define DEVFN static __device__ __forceinline__

typedef __attribute__((ext_vector_type(8))) short short8;
typedef __attribute__((ext_vector_type(4))) float f32x4;

DEVFN float selu_f(float v) {
    const float scale = 1.0507009873554805f;
    const float alpha = 1.6732632423543772f;
    return v > 0.f ? scale * v : scale * alpha * (expf(v) - 1.f);
}

DEVFN float lrelu02(float v) { return v > 0.f ? v : 0.2f * v; }

// truncation split: hi = trunc_bf16(a); lo = trunc_bf16(a - hi)
DEVFN void split_bf16(float a, unsigned short& hi, unsigned short& lo) {
    unsigned u = __float_as_uint(a);
    hi = (unsigned short)(u >> 16);
    float hf = __uint_as_float(u & 0xFFFF0000u);
    float l = a - hf;
    lo = (unsigned short)(__float_as_uint(l) >> 16);
}

// ---------------- CNN ----------------
__global__ void conv3x3_selu(const float* __restrict__ in, const float* __restrict__ w,
                             const float* __restrict__ b, float* __restrict__ out,
                             int Cin, int Cout) {
    int t = blockIdx.x * blockDim.x + threadIdx.x;
    if (t >= Cout * 4096) return;
    int pix = t & 4095;
    int co  = t >> 12;
    int y = pix >> 6, x = pix & 63;
    float acc = b[co];
    for (int ci = 0; ci < Cin; ++ci) {
        const float* ip = in + ci * 4096;
        const float* wp = w + (co * Cin + ci) * 9;
#pragma unroll
        for (int ky = 0; ky < 3; ++ky) {
            int yy = y + ky - 1;
            if (yy < 0 || yy > 63) continue;
#pragma unroll
            for (int kx = 0; kx < 3; ++kx) {
                int xx = x + kx - 1;
                if (xx < 0 || xx > 63) continue;
                acc += ip[yy * 64 + xx] * wp[ky * 3 + kx];
            }
        }
    }
    out[t] = selu_f(acc);
}

__global__ void avgpool_c(const float* __restrict__ in, float* __restrict__ gfeat) {
    int c = blockIdx.x;            // 24 blocks
    int t = threadIdx.x;           // 256 threads
    float s = 0.f;
    for (int i = t; i < 4096; i += 256) s += in[c * 4096 + i];
#pragma unroll
    for (int off = 32; off >= 1; off >>= 1) s += __shfl_xor(s, off);
    __shared__ float red[4];
    int wave = t >> 6, lane = t & 63;
    if (lane == 0) red[wave] = s;
    __syncthreads();
    if (t == 0) gfeat[c] = (red[0] + red[1] + red[2] + red[3]) * (1.f / 4096.f);
}

// ---------------- node feature init (padded to 48 ch, fp16) + masks ---------
__global__ void build_h0(const float* __restrict__ x, const float* __restrict__ gfeat,
                         __half* __restrict__ h0f, unsigned* __restrict__ masks, int N) {
    int n = blockIdx.x * blockDim.x + threadIdx.x;
    if (n >= N) return;
    float x0 = x[n * 10 + 0], x1 = x[n * 10 + 1];
    unsigned mk = (x0 == 1.f ? 1u : 0u) | (x0 == 0.f ? 2u : 0u) |
                  (x1 == 0.f ? 4u : 0u) | (x1 == 1.f ? 8u : 0u);
    masks[n] = mk;
    __half* hq = h0f + (size_t)n * 48;
#pragma unroll
    for (int j = 0; j < 48; ++j) {
        float v = (j < 24) ? gfeat[j] : (j < 34 ? x[n * 10 + (j - 24)] : 0.f);
        hq[j] = __float2half(v);
    }
}

// ---------------- CSR build ----------------
__global__ void count_dst(const int* __restrict__ ei, int* __restrict__ cnt, int E, int N) {
    int t = blockIdx.x * blockDim.x + threadIdx.x;
    if (t >= E + N) return;
    int dst = (t < E) ? ei[E + t] : (t - E);
    atomicAdd(&cnt[dst], 1);
}

__global__ void exscan_single(const int* __restrict__ cnt, int* __restrict__ indptr, int n) {
    __shared__ int sdata[256];
    __shared__ int run_s;
    int tid = threadIdx.x;
    if (tid == 0) { run_s = 0; indptr[0] = 0; }
    __syncthreads();
    for (int base = 0; base < n; base += 256) {
        int i = base + tid;
        int v = (i < n) ? cnt[i] : 0;
        sdata[tid] = v;
        __syncthreads();
        for (int off = 1; off < 256; off <<= 1) {
            int tmp = (tid >= off) ? sdata[tid - off] : 0;
            __syncthreads();
            sdata[tid] += tmp;
            __syncthreads();
        }
        if (i < n) indptr[i + 1] = run_s + sdata[tid];
        __syncthreads();
        if (tid == 0) run_s += sdata[255];
        __syncthreads();
    }
}

__global__ void copy_int(const int* __restrict__ a, int* __restrict__ b, int n) {
    int t = blockIdx.x * blockDim.x + threadIdx.x;
    if (t < n) b[t] = a[t];
}

__global__ void scatter_edges(const int* __restrict__ ei, int* __restrict__ cursor,
                              int* __restrict__ col, int E, int N) {
    int t = blockIdx.x * blockDim.x + threadIdx.x;
    if (t >= E + N) return;
    int src, dst;
    if (t < E) { src = ei[t]; dst = ei[E + t]; }
    else       { src = dst = t - E; }
    int pos = atomicAdd(&cursor[dst], 1);
    col[pos] = src;
}

// ---------------- weight prep ----------------------------------------------
__global__ void build_wesed(const float* __restrict__ W, const float* __restrict__ as,
                            const float* __restrict__ ad, float* __restrict__ wesed,
                            int K, int Kp, int H, int C) {
    int H2 = 2 * H;
    int t = blockIdx.x * blockDim.x + threadIdx.x;
    if (t >= Kp * H2) return;
    int k = t / H2, o = t - k * H2;
    float s = 0.f;
    if (k < K) {
        int h = (o < H) ? o : o - H;
        const float* av = ((o < H) ? as : ad) + h * C;
        const float* wp = W + (size_t)k * (H * C) + h * C;
        for (int c = 0; c < C; ++c) s += wp[c] * av[c];
    }
    wesed[t] = s;
}

// Bt_hi/Bt_lo[m * KA + (h*Kp + k)] = split_bf16(W[k, h*C+m]), 0 pad for k>=K
__global__ void build_wtb(const float* __restrict__ W, unsigned short* __restrict__ bhi,
                          unsigned short* __restrict__ blo, int K, int Kp, int H, int C) {
    int KA = H * Kp;
    int t = blockIdx.x * blockDim.x + threadIdx.x;
    if (t >= C * KA) return;
    int ka = t % KA;
    int m  = t / KA;
    int h = ka / Kp, k = ka - h * Kp;
    float v = (k < K) ? W[(size_t)k * (H * C) + h * C + m] : 0.f;
    unsigned short hi, lo;
    split_bf16(v, hi, lo);
    bhi[t] = hi;
    blo[t] = lo;
}

// wstack[(h*Kp+k)*C + c] = W[k, h*C+c] (fp32; final layer C=2)
__global__ void build_wstack(const float* __restrict__ W, float* __restrict__ ws,
                             int K, int Kp, int H, int C) {
    int t = blockIdx.x * blockDim.x + threadIdx.x;
    if (t >= H * Kp * C) return;
    int c = t % C;
    int r = t / C;
    int h = r / Kp, k = r - h * Kp;
    ws[t] = (k < K) ? W[(size_t)k * (H * C) + h * C + c] : 0.f;
}

// ---------------- es/ed: esed[n, o] = hin16[n,:] @ wesed[:,o], o < 2H -------
__global__ void esed_kernel(const __half* __restrict__ hin, const float* __restrict__ wesed,
                            float* __restrict__ esed, int N, int Kp, int H2) {
    int t = blockIdx.x * blockDim.x + threadIdx.x;
    if (t >= N * H2) return;
    int n = t / H2, o = t - n * H2;
    const __half* hp = hin + (size_t)n * Kp;
    float s = 0.f;
    for (int k = 0; k < Kp; ++k) s += __half2float(hp[k]) * wesed[k * H2 + o];
    esed[t] = s;
}

// ---------------- attention: max pass + fp16 numerators + (1/H)/z -----------
__global__ void attn_kernel(const float* __restrict__ esed,
                            const int* __restrict__ indptr, const int* __restrict__ col,
                            __half* __restrict__ palpha, float* __restrict__ zinv,
                            int N, int H) {
    int t = blockIdx.x * blockDim.x + threadIdx.x;
    if (t >= N * H) return;
    int n = t / H, h = t - n * H;
    int H2 = 2 * H;
    float edv = esed[n * H2 + H + h];
    int beg = indptr[n], end = indptr[n + 1];
    float mv = -3.4e38f;
    for (int i = beg; i < end; ++i) {
        float e = lrelu02(esed[col[i] * H2 + h] + edv);
        mv = fmaxf(mv, e);
    }
    float z = 0.f;
    for (int i = beg; i < end; ++i) {
        float e = lrelu02(esed[col[i] * H2 + h] + edv);
        __half ph = __float2half(expf(e - mv));
        palpha[(size_t)i * H + h] = ph;
        z += __half2float(ph);
    }
    zinv[t] = (1.f / H) / (z + 1e-16f);
}

// ---------------- gather: g[n, h*KP+k] = zinv * Sum_e p * hin16[src, k] -----
template <int H, int KP, int NPB>
__global__ __launch_bounds__(NPB * KP / 2) void gat_gather(
        const __half* __restrict__ hinf, const __half* __restrict__ palpha,
        const float* __restrict__ zinv, const int* __restrict__ indptr,
        const int* __restrict__ col, __half* __restrict__ g, int N) {
    const int TPN = KP / 2;
    int sub = threadIdx.x / TPN;
    int j   = threadIdx.x % TPN;
    int n = blockIdx.x * NPB + sub;
    if (n >= N) return;
    int c0 = j * 2;
    float acc[H][2];
#pragma unroll
    for (int h = 0; h < H; ++h) { acc[h][0] = 0.f; acc[h][1] = 0.f; }
    int beg = indptr[n], end = indptr[n + 1];
    for (int i = beg; i < end; ++i) {
        int src = col[i];
        __half2 hv = *(const __half2*)(hinf + (size_t)src * KP + c0);
        float2 f = __half22float2(hv);
        const __half2* ap = (const __half2*)(palpha + (size_t)i * H);
#pragma unroll
        for (int h2 = 0; h2 < H / 2; ++h2) {
            float2 aa = __half22float2(ap[h2]);
            acc[2 * h2 + 0][0] += aa.x * f.x;
            acc[2 * h2 + 0][1] += aa.x * f.y;
            acc[2 * h2 + 1][0] += aa.y * f.x;
            acc[2 * h2 + 1][1] += aa.y * f.y;
        }
    }
    __half* gp = g + (size_t)n * (H * KP) + c0;
#pragma unroll
    for (int h = 0; h < H; ++h) {
        float zf = zinv[n * H + h];
        *(__half2*)(gp + h * KP) = __floats2half2_rn(acc[h][0] * zf, acc[h][1] * zf);
    }
}

// ---------------- pipelined no-LDS MFMA GEMM --------------------------------
// O16 = bfix(selu(A @ Bt^T + bias)); A fp16 [N x K], Bt hi/lo [M x K] planes.
// grid (N/16), NW waves/block; wave w: 16 rows x cols [w*64, w*64+64).
// K % 128 == 0. A prefetch depth 4 (rotating regs, static under unroll).
template <int NW>
__global__ __launch_bounds__(NW * 64) void gemm16(const __half* __restrict__ A,
                                                  const unsigned short* __restrict__ Bhi,
                                                  const unsigned short* __restrict__ Blo,
                                                  const float* __restrict__ bias,
                                                  const unsigned* __restrict__ masks,
                                                  __half* __restrict__ O16,
                                                  int N, int K, int M) {
    int tid  = threadIdx.x;
    int wave = tid >> 6;
    int lane = tid & 63;
    int ln16 = lane & 15;
    int q    = lane >> 4;                 // 0..3 (k-octet)
    int row0 = blockIdx.x * 16;
    int col0 = wave * 64;

    const __half* ap = A + (size_t)(row0 + ln16) * K + q * 8;
    const unsigned short* bhp = Bhi + (size_t)(col0 + ln16) * K + q * 8;
    const unsigned short* blp = Blo + (size_t)(col0 + ln16) * K + q * 8;

    f32x4 acc[4];
#pragma unroll
    for (int j = 0; j < 4; ++j) acc[j] = (f32x4){0.f, 0.f, 0.f, 0.f};

    // preload A prefetch pipeline (K >= 128 guaranteed)
    short8 apf[4];
#pragma unroll
    for (int d = 0; d < 4; ++d) apf[d] = *(const short8*)(ap + d * 32);

    for (int k0 = 0; k0 < K; k0 += 128) {
#pragma unroll
        for (int u = 0; u < 4; ++u) {
            int kc = k0 + u * 32;
            // B loads for this chunk (L2-resident)
            short8 bh[4], bl[4];
#pragma unroll
            for (int j = 0; j < 4; ++j) {
                bh[j] = *(const short8*)(bhp + (size_t)j * 16 * K + kc);
                bl[j] = *(const short8*)(blp + (size_t)j * 16 * K + kc);
            }
            // consume current A chunk, refill slot with kc+128
            short8 araw = apf[u];
            int kpf = kc + 128;
            if (kpf > K - 32) kpf = K - 32;     // clamped dummy prefetch at tail
            apf[u] = *(const short8*)(ap + kpf);
            // split A fp16 -> bf16 hi/lo (exact: fp16 fits in 2x bf16)
            short8 ah, al;
#pragma unroll
            for (int i = 0; i < 8; ++i) {
                __half_raw hr;
                hr.x = (unsigned short)araw[i];
                float f = __half2float(*(const __half*)&hr);
                unsigned uu = __float_as_uint(f);
                ah[i] = (short)(uu >> 16);
                float lf = f - __uint_as_float(uu & 0xFFFF0000u);
                al[i] = (short)(__float_as_uint(lf) >> 16);
            }
#pragma unroll
            for (int j = 0; j < 4; ++j) {
                acc[j] = __builtin_amdgcn_mfma_f32_16x16x32_bf16(ah, bh[j], acc[j], 0, 0, 0);
                acc[j] = __builtin_amdgcn_mfma_f32_16x16x32_bf16(ah, bl[j], acc[j], 0, 0, 0);
                acc[j] = __builtin_amdgcn_mfma_f32_16x16x32_bf16(al, bh[j], acc[j], 0, 0, 0);
            }
        }
    }

    // C/D layout: col = lane&15, row = (lane>>4)*4 + reg
#pragma unroll
    for (int j = 0; j < 4; ++j) {
        int cc = col0 + j * 16 + ln16;
        float bv = bias[cc];
#pragma unroll
        for (int r = 0; r < 4; ++r) {
            int rr = row0 + q * 4 + r;
            float v = selu_f(acc[j][r] + bv);
            if (cc < 2) {
                unsigned mk = masks[rr];
                if (cc == 0) { if (mk & 2u) v = 0.f; else if (mk & 1u) v = 1.f; }
                else         { if (mk & 8u) v = 1.f; else if (mk & 4u) v = 0.f; }
            }
            O16[(size_t)rr * M + cc] = __float2half(v);
        }
    }
}

// ---------------- final layer (C=2): out = bfix(x + selu(g @ W5s + b5)) -----
__global__ __launch_bounds__(256) void final5_kernel(const __half* __restrict__ g,
                                                     const float* __restrict__ W5,
                                                     const float* __restrict__ b5,
                                                     const unsigned* __restrict__ masks,
                                                     const float* __restrict__ x,
                                                     float* __restrict__ out,
                                                     int N, int KA) {
    int wave = threadIdx.x >> 6, lane = threadIdx.x & 63;
    int n = blockIdx.x * 4 + wave;
    if (n >= N) return;
    float a0 = 0.f, a1 = 0.f;
    const __half* gp = g + (size_t)n * KA;
    for (int k = lane * 2; k < KA; k += 128) {
        float2 f = __half22float2(*(const __half2*)(gp + k));
        float4 w = *(const float4*)(W5 + (size_t)k * 2);
        a0 += f.x * w.x + f.y * w.z;
        a1 += f.x * w.y + f.y * w.w;
    }
#pragma unroll
    for (int off = 32; off >= 1; off >>= 1) {
        a0 += __shfl_xor(a0, off);
        a1 += __shfl_xor(a1, off);
    }
    if (lane == 0) {
        unsigned mk = masks[n];
        float v0 = x[n * 10 + 0] + selu_f(a0 + b5[0]);
        float v1 = x[n * 10 + 1] + selu_f(a1 + b5[1]);
        if (mk & 2u) v0 = 0.f; else if (mk & 1u) v0 = 1.f;
        if (mk & 8u) v1 = 1.f; else if (mk & 4u) v1 = 0.f;
        out[n * 2 + 0] = v0;
        out[n * 2 + 1] = v1;
    }
}

// ---------------------------------------------------------------------------
extern "C" void kernel_launch(void* const* d_in, const int* in_sizes, int n_in,
                              void* d_out, int out_size, void* d_ws, size_t ws_size,
                              hipStream_t stream) {
    const float* x   = (const float*)d_in[0];
    const int*   ei  = (const int*)d_in[1];
    const float* cf  = (const float*)d_in[2];
    const float* cw[4] = {(const float*)d_in[3], (const float*)d_in[5],
                          (const float*)d_in[7], (const float*)d_in[9]};
    const float* cb[4] = {(const float*)d_in[4], (const float*)d_in[6],
                          (const float*)d_in[8], (const float*)d_in[10]};
    const float* gw[5], *gas[5], *gad[5], *gb[5];
    for (int i = 0; i < 5; ++i) {
        gw[i]  = (const float*)d_in[11 + 4 * i];
        gas[i] = (const float*)d_in[12 + 4 * i];
        gad[i] = (const float*)d_in[13 + 4 * i];
        gb[i]  = (const float*)d_in[14 + 4 * i];
    }
    const int N = in_sizes[0] / 10;        // 10000
    const int E = in_sizes[1] / 2;         // 160000
    const int EN = E + N;

    // ---- workspace carve-up ----
    char* base = (char*)d_ws;
    size_t off = 0;
    auto alloc = [&](size_t bytes) -> char* {
        char* p = base + off;
        off = (off + bytes + 255) & ~(size_t)255;
        return p;
    };
    float* c1    = (float*)alloc(16 * 4096 * 4);
    float* c2    = (float*)alloc(32 * 4096 * 4);
    float* c3    = (float*)alloc(64 * 4096 * 4);
    float* c4    = (float*)alloc(24 * 4096 * 4);
    float* gfeat = (float*)alloc(24 * 4);
    __half* hA16 = (__half*)alloc((size_t)N * 256 * 2);
    __half* hB16 = (__half*)alloc((size_t)N * 256 * 2);
    __half* g    = (__half*)alloc((size_t)N * 2048 * 2);
    float* esed  = (float*)alloc((size_t)N * 32 * 4);
    float* zinv  = (float*)alloc((size_t)N * 16 * 4);
    __half* palpha = (__half*)alloc((size_t)EN * 16 * 2);
    float* wesed = (float*)alloc(256 * 32 * 4);
    float* wstack= (float*)alloc((size_t)2048 * 2 * 4);
    unsigned short* bt_hi = (unsigned short*)alloc((size_t)262144 * 2);
    unsigned short* bt_lo = (unsigned short*)alloc((size_t)262144 * 2);
    unsigned* masks = (unsigned*)alloc((size_t)N * 4);
    int* cnt    = (int*)alloc((size_t)N * 4);
    int* indptr = (int*)alloc((size_t)(N + 1) * 4);
    int* cursor = (int*)alloc((size_t)N * 4);
    int* col    = (int*)alloc((size_t)EN * 4);
    (void)ws_size; // ~70 MB

    // ---- CNN ----
    conv3x3_selu<<<(16 * 4096 + 255) / 256, 256, 0, stream>>>(cf, cw[0], cb[0], c1, 4, 16);
    conv3x3_selu<<<(32 * 4096 + 255) / 256, 256, 0, stream>>>(c1, cw[1], cb[1], c2, 16, 32);
    conv3x3_selu<<<(64 * 4096 + 255) / 256, 256, 0, stream>>>(c2, cw[2], cb[2], c3, 32, 64);
    conv3x3_selu<<<(24 * 4096 + 255) / 256, 256, 0, stream>>>(c3, cw[3], cb[3], c4, 64, 24);
    avgpool_c<<<24, 256, 0, stream>>>(c4, gfeat);

    // ---- h0 (padded to 48, fp16) + masks ----
    build_h0<<<(N + 255) / 256, 256, 0, stream>>>(x, gfeat, hA16, masks, N);

    // ---- CSR by dst (incl self loops) ----
    hipMemsetAsync(cnt, 0, (size_t)N * 4, stream);
    count_dst<<<(EN + 255) / 256, 256, 0, stream>>>(ei, cnt, E, N);
    exscan_single<<<1, 256, 0, stream>>>(cnt, indptr, N);
    copy_int<<<(N + 255) / 256, 256, 0, stream>>>(indptr, cursor, N);
    scatter_edges<<<(EN + 255) / 256, 256, 0, stream>>>(ei, cursor, col, E, N);

    // ---- GAT layers ----
    const int Ko[5] = {34, 64, 128, 256, 128};   // true input dims
    const int Kp[5] = {48, 64, 128, 256, 128};   // padded (KA % 128 == 0)
    const int Hs[5] = {8, 16, 8, 8, 16};
    const int Cs[5] = {64, 128, 256, 128, 2};

    const __half* hin16 = hA16;
    __half* hout16[4]  = {hB16, hA16, hB16, hA16};

    for (int lyr = 0; lyr < 5; ++lyr) {
        int K = Ko[lyr], KP = Kp[lyr], H = Hs[lyr], C = Cs[lyr];
        int KA = H * KP;
        build_wesed<<<(KP * 2 * H + 255) / 256, 256, 0, stream>>>(gw[lyr], gas[lyr], gad[lyr],
                                                                  wesed, K, KP, H, C);
        esed_kernel<<<(N * 2 * H + 255) / 256, 256, 0, stream>>>(hin16, wesed, esed, N, KP, 2 * H);
        attn_kernel<<<(N * H + 255) / 256, 256, 0, stream>>>(esed, indptr, col, palpha, zinv, N, H);
        if (lyr == 0)
            gat_gather<8, 48, 10><<<(N + 9) / 10, 240, 0, stream>>>(hin16, palpha, zinv, indptr, col, g, N);
        else if (lyr == 1)
            gat_gather<16, 64, 8><<<(N + 7) / 8, 256, 0, stream>>>(hin16, palpha, zinv, indptr, col, g, N);
        else if (lyr == 2)
            gat_gather<8, 128, 4><<<(N + 3) / 4, 256, 0, stream>>>(hin16, palpha, zinv, indptr, col, g, N);
        else if (lyr == 3)
            gat_gather<8, 256, 2><<<(N + 1) / 2, 256, 0, stream>>>(hin16, palpha, zinv, indptr, col, g, N);
        else
            gat_gather<16, 128, 4><<<(N + 3) / 4, 256, 0, stream>>>(hin16, palpha, zinv, indptr, col, g, N);

        if (lyr < 4) {
            build_wtb<<<(C * KA + 255) / 256, 256, 0, stream>>>(gw[lyr], bt_hi, bt_lo, K, KP, H, C);
            if (C == 64)
                gemm16<1><<<N / 16, 64, 0, stream>>>(g, bt_hi, bt_lo, gb[lyr], masks, hout16[lyr], N, KA, C);
            else if (C == 128)
                gemm16<2><<<N / 16, 128, 0, stream>>>(g, bt_hi, bt_lo, gb[lyr], masks, hout16[lyr], N, KA, C);
            else
                gemm16<4><<<N / 16, 256, 0, stream>>>(g, bt_hi, bt_lo, gb[lyr], masks, hout16[lyr], N, KA, C);
            hin16 = hout16[lyr];
        } else {
            build_wstack<<<(KA * 2 + 255) / 256, 256, 0, stream>>>(gw[4], wstack, K, KP, H, 2);
            final5_kernel<<<(N + 3) / 4, 256, 0, stream>>>(g, wstack, gb[4], masks, x,
                                                           (float*)d_out, N, KA);
        }
    }
}

// Round 7
// 1108.011 us; speedup vs baseline: 1.3530x; 1.0095x over previous
//
#include <hip/hip_runtime.h>
#include <hip/hip_fp16.h>
#include <math.h>

// ---------------------------------------------------------------------------
// NetGlobGATFix. R7: dense no-LDS MFMA GEMM.
//   - gemm32: 32 rows/block (2 row-tiles per wave), NW=M/64 waves; per chunk
//     12 loads -> 24 MFMA; B fragments reused across row tiles.
//   - g stored as pre-split bf16 hi/lo planes (split done in gather epilogue
//     from fp32) -> no VALU split in GEMM K-loop, fp32-quality A.
//   - esed half2-vectorized.
// ---------------------------------------------------------------------------

#define DEVFN static __device__ __forceinline__

typedef __attribute__((ext_vector_type(8))) short short8;
typedef __attribute__((ext_vector_type(4))) float f32x4;

DEVFN float selu_f(float v) {
    const float scale = 1.0507009873554805f;
    const float alpha = 1.6732632423543772f;
    return v > 0.f ? scale * v : scale * alpha * (expf(v) - 1.f);
}

DEVFN float lrelu02(float v) { return v > 0.f ? v : 0.2f * v; }

// truncation split: hi = trunc_bf16(a); lo = trunc_bf16(a - hi)
DEVFN void split_bf16(float a, unsigned short& hi, unsigned short& lo) {
    unsigned u = __float_as_uint(a);
    hi = (unsigned short)(u >> 16);
    float hf = __uint_as_float(u & 0xFFFF0000u);
    float l = a - hf;
    lo = (unsigned short)(__float_as_uint(l) >> 16);
}

DEVFN float bf16_to_f(unsigned short h) {
    return __uint_as_float((unsigned)h << 16);
}

// ---------------- CNN ----------------
__global__ void conv3x3_selu(const float* __restrict__ in, const float* __restrict__ w,
                             const float* __restrict__ b, float* __restrict__ out,
                             int Cin, int Cout) {
    int t = blockIdx.x * blockDim.x + threadIdx.x;
    if (t >= Cout * 4096) return;
    int pix = t & 4095;
    int co  = t >> 12;
    int y = pix >> 6, x = pix & 63;
    float acc = b[co];
    for (int ci = 0; ci < Cin; ++ci) {
        const float* ip = in + ci * 4096;
        const float* wp = w + (co * Cin + ci) * 9;
#pragma unroll
        for (int ky = 0; ky < 3; ++ky) {
            int yy = y + ky - 1;
            if (yy < 0 || yy > 63) continue;
#pragma unroll
            for (int kx = 0; kx < 3; ++kx) {
                int xx = x + kx - 1;
                if (xx < 0 || xx > 63) continue;
                acc += ip[yy * 64 + xx] * wp[ky * 3 + kx];
            }
        }
    }
    out[t] = selu_f(acc);
}

__global__ void avgpool_c(const float* __restrict__ in, float* __restrict__ gfeat) {
    int c = blockIdx.x;            // 24 blocks
    int t = threadIdx.x;           // 256 threads
    float s = 0.f;
    for (int i = t; i < 4096; i += 256) s += in[c * 4096 + i];
#pragma unroll
    for (int off = 32; off >= 1; off >>= 1) s += __shfl_xor(s, off);
    __shared__ float red[4];
    int wave = t >> 6, lane = t & 63;
    if (lane == 0) red[wave] = s;
    __syncthreads();
    if (t == 0) gfeat[c] = (red[0] + red[1] + red[2] + red[3]) * (1.f / 4096.f);
}

// ---------------- node feature init (padded to 48 ch, fp16) + masks ---------
__global__ void build_h0(const float* __restrict__ x, const float* __restrict__ gfeat,
                         __half* __restrict__ h0f, unsigned* __restrict__ masks, int N) {
    int n = blockIdx.x * blockDim.x + threadIdx.x;
    if (n >= N) return;
    float x0 = x[n * 10 + 0], x1 = x[n * 10 + 1];
    unsigned mk = (x0 == 1.f ? 1u : 0u) | (x0 == 0.f ? 2u : 0u) |
                  (x1 == 0.f ? 4u : 0u) | (x1 == 1.f ? 8u : 0u);
    masks[n] = mk;
    __half* hq = h0f + (size_t)n * 48;
#pragma unroll
    for (int j = 0; j < 48; ++j) {
        float v = (j < 24) ? gfeat[j] : (j < 34 ? x[n * 10 + (j - 24)] : 0.f);
        hq[j] = __float2half(v);
    }
}

// ---------------- CSR build ----------------
__global__ void count_dst(const int* __restrict__ ei, int* __restrict__ cnt, int E, int N) {
    int t = blockIdx.x * blockDim.x + threadIdx.x;
    if (t >= E + N) return;
    int dst = (t < E) ? ei[E + t] : (t - E);
    atomicAdd(&cnt[dst], 1);
}

__global__ void exscan_single(const int* __restrict__ cnt, int* __restrict__ indptr, int n) {
    __shared__ int sdata[256];
    __shared__ int run_s;
    int tid = threadIdx.x;
    if (tid == 0) { run_s = 0; indptr[0] = 0; }
    __syncthreads();
    for (int base = 0; base < n; base += 256) {
        int i = base + tid;
        int v = (i < n) ? cnt[i] : 0;
        sdata[tid] = v;
        __syncthreads();
        for (int off = 1; off < 256; off <<= 1) {
            int tmp = (tid >= off) ? sdata[tid - off] : 0;
            __syncthreads();
            sdata[tid] += tmp;
            __syncthreads();
        }
        if (i < n) indptr[i + 1] = run_s + sdata[tid];
        __syncthreads();
        if (tid == 0) run_s += sdata[255];
        __syncthreads();
    }
}

__global__ void copy_int(const int* __restrict__ a, int* __restrict__ b, int n) {
    int t = blockIdx.x * blockDim.x + threadIdx.x;
    if (t < n) b[t] = a[t];
}

__global__ void scatter_edges(const int* __restrict__ ei, int* __restrict__ cursor,
                              int* __restrict__ col, int E, int N) {
    int t = blockIdx.x * blockDim.x + threadIdx.x;
    if (t >= E + N) return;
    int src, dst;
    if (t < E) { src = ei[t]; dst = ei[E + t]; }
    else       { src = dst = t - E; }
    int pos = atomicAdd(&cursor[dst], 1);
    col[pos] = src;
}

// ---------------- weight prep ----------------------------------------------
__global__ void build_wesed(const float* __restrict__ W, const float* __restrict__ as,
                            const float* __restrict__ ad, float* __restrict__ wesed,
                            int K, int Kp, int H, int C) {
    int H2 = 2 * H;
    int t = blockIdx.x * blockDim.x + threadIdx.x;
    if (t >= Kp * H2) return;
    int k = t / H2, o = t - k * H2;
    float s = 0.f;
    if (k < K) {
        int h = (o < H) ? o : o - H;
        const float* av = ((o < H) ? as : ad) + h * C;
        const float* wp = W + (size_t)k * (H * C) + h * C;
        for (int c = 0; c < C; ++c) s += wp[c] * av[c];
    }
    wesed[t] = s;
}

// Bt_hi/Bt_lo[m * KA + (h*Kp + k)] = split_bf16(W[k, h*C+m]), 0 pad for k>=K
__global__ void build_wtb(const float* __restrict__ W, unsigned short* __restrict__ bhi,
                          unsigned short* __restrict__ blo, int K, int Kp, int H, int C) {
    int KA = H * Kp;
    int t = blockIdx.x * blockDim.x + threadIdx.x;
    if (t >= C * KA) return;
    int ka = t % KA;
    int m  = t / KA;
    int h = ka / Kp, k = ka - h * Kp;
    float v = (k < K) ? W[(size_t)k * (H * C) + h * C + m] : 0.f;
    unsigned short hi, lo;
    split_bf16(v, hi, lo);
    bhi[t] = hi;
    blo[t] = lo;
}

// wstack[(h*Kp+k)*C + c] = W[k, h*C+c] (fp32; final layer C=2)
__global__ void build_wstack(const float* __restrict__ W, float* __restrict__ ws,
                             int K, int Kp, int H, int C) {
    int t = blockIdx.x * blockDim.x + threadIdx.x;
    if (t >= H * Kp * C) return;
    int c = t % C;
    int r = t / C;
    int h = r / Kp, k = r - h * Kp;
    ws[t] = (k < K) ? W[(size_t)k * (H * C) + h * C + c] : 0.f;
}

// ---------------- es/ed: esed[n, o] = hin16[n,:] @ wesed[:,o], o < 2H -------
__global__ void esed_kernel(const __half* __restrict__ hin, const float* __restrict__ wesed,
                            float* __restrict__ esed, int N, int Kp, int H2) {
    int t = blockIdx.x * blockDim.x + threadIdx.x;
    if (t >= N * H2) return;
    int n = t / H2, o = t - n * H2;
    const __half2* hp = (const __half2*)(hin + (size_t)n * Kp);
    float s = 0.f;
    for (int k2 = 0; k2 < Kp / 2; ++k2) {
        float2 f = __half22float2(hp[k2]);
        s += f.x * wesed[(2 * k2) * H2 + o] + f.y * wesed[(2 * k2 + 1) * H2 + o];
    }
    esed[t] = s;
}

// ---------------- attention: max pass + fp16 numerators + (1/H)/z -----------
__global__ void attn_kernel(const float* __restrict__ esed,
                            const int* __restrict__ indptr, const int* __restrict__ col,
                            __half* __restrict__ palpha, float* __restrict__ zinv,
                            int N, int H) {
    int t = blockIdx.x * blockDim.x + threadIdx.x;
    if (t >= N * H) return;
    int n = t / H, h = t - n * H;
    int H2 = 2 * H;
    float edv = esed[n * H2 + H + h];
    int beg = indptr[n], end = indptr[n + 1];
    float mv = -3.4e38f;
    for (int i = beg; i < end; ++i) {
        float e = lrelu02(esed[col[i] * H2 + h] + edv);
        mv = fmaxf(mv, e);
    }
    float z = 0.f;
    for (int i = beg; i < end; ++i) {
        float e = lrelu02(esed[col[i] * H2 + h] + edv);
        __half ph = __float2half(expf(e - mv));
        palpha[(size_t)i * H + h] = ph;
        z += __half2float(ph);
    }
    zinv[t] = (1.f / H) / (z + 1e-16f);
}

// ------- gather: g{hi,lo}[n, h*KP+k] = split(zinv * Sum_e p * hin16[src,k]) -
template <int H, int KP, int NPB>
__global__ __launch_bounds__(NPB * KP / 2) void gat_gather(
        const __half* __restrict__ hinf, const __half* __restrict__ palpha,
        const float* __restrict__ zinv, const int* __restrict__ indptr,
        const int* __restrict__ col, unsigned short* __restrict__ ghi,
        unsigned short* __restrict__ glo, int N) {
    const int TPN = KP / 2;
    int sub = threadIdx.x / TPN;
    int j   = threadIdx.x % TPN;
    int n = blockIdx.x * NPB + sub;
    if (n >= N) return;
    int c0 = j * 2;
    float acc[H][2];
#pragma unroll
    for (int h = 0; h < H; ++h) { acc[h][0] = 0.f; acc[h][1] = 0.f; }
    int beg = indptr[n], end = indptr[n + 1];
    for (int i = beg; i < end; ++i) {
        int src = col[i];
        __half2 hv = *(const __half2*)(hinf + (size_t)src * KP + c0);
        float2 f = __half22float2(hv);
        const __half2* ap = (const __half2*)(palpha + (size_t)i * H);
#pragma unroll
        for (int h2 = 0; h2 < H / 2; ++h2) {
            float2 aa = __half22float2(ap[h2]);
            acc[2 * h2 + 0][0] += aa.x * f.x;
            acc[2 * h2 + 0][1] += aa.x * f.y;
            acc[2 * h2 + 1][0] += aa.y * f.x;
            acc[2 * h2 + 1][1] += aa.y * f.y;
        }
    }
    size_t base = (size_t)n * (H * KP) + c0;
#pragma unroll
    for (int h = 0; h < H; ++h) {
        float zf = zinv[n * H + h];
        unsigned short h0, l0, h1, l1;
        split_bf16(acc[h][0] * zf, h0, l0);
        split_bf16(acc[h][1] * zf, h1, l1);
        ushort2 uh; uh.x = h0; uh.y = h1;
        ushort2 ul; ul.x = l0; ul.y = l1;
        *(ushort2*)(ghi + base + h * KP) = uh;
        *(ushort2*)(glo + base + h * KP) = ul;
    }
}

// ---------------- dense no-LDS MFMA GEMM ------------------------------------
// O16 = bfix(selu(A @ Bt^T + bias)); A bf16 hi/lo planes [N x K],
// Bt hi/lo planes [M x K]. grid ceil(N/32), NW waves; wave w: rows
// [row0,row0+32) x cols [w*64, w*64+64) via 2 row-tiles. K % 32 == 0.
template <int NW>
__global__ __launch_bounds__(NW * 64) void gemm32(const unsigned short* __restrict__ Ahi,
                                                  const unsigned short* __restrict__ Alo,
                                                  const unsigned short* __restrict__ Bhi,
                                                  const unsigned short* __restrict__ Blo,
                                                  const float* __restrict__ bias,
                                                  const unsigned* __restrict__ masks,
                                                  __half* __restrict__ O16,
                                                  int N, int K, int M) {
    int tid  = threadIdx.x;
    int wave = tid >> 6;
    int lane = tid & 63;
    int ln16 = lane & 15;
    int q    = lane >> 4;                 // 0..3 (k-octet)
    int row0 = blockIdx.x * 32;
    int col0 = wave * 64;

    const unsigned short* a0h = Ahi + (size_t)(row0 + ln16) * K + q * 8;
    const unsigned short* a0l = Alo + (size_t)(row0 + ln16) * K + q * 8;
    const unsigned short* bhp = Bhi + (size_t)(col0 + ln16) * K + q * 8;
    const unsigned short* blp = Blo + (size_t)(col0 + ln16) * K + q * 8;
    const size_t rstep = (size_t)16 * K;

    f32x4 acc[2][4];
#pragma unroll
    for (int rt = 0; rt < 2; ++rt)
#pragma unroll
        for (int j = 0; j < 4; ++j) acc[rt][j] = (f32x4){0.f, 0.f, 0.f, 0.f};

#pragma unroll 2
    for (int kc = 0; kc < K; kc += 32) {
        short8 bh[4], bl[4];
#pragma unroll
        for (int j = 0; j < 4; ++j) {
            bh[j] = *(const short8*)(bhp + (size_t)j * rstep + kc);
            bl[j] = *(const short8*)(blp + (size_t)j * rstep + kc);
        }
        short8 ah0 = *(const short8*)(a0h + kc);
        short8 al0 = *(const short8*)(a0l + kc);
        short8 ah1 = *(const short8*)(a0h + rstep + kc);
        short8 al1 = *(const short8*)(a0l + rstep + kc);
#pragma unroll
        for (int j = 0; j < 4; ++j) {
            acc[0][j] = __builtin_amdgcn_mfma_f32_16x16x32_bf16(ah0, bh[j], acc[0][j], 0, 0, 0);
            acc[0][j] = __builtin_amdgcn_mfma_f32_16x16x32_bf16(ah0, bl[j], acc[0][j], 0, 0, 0);
            acc[0][j] = __builtin_amdgcn_mfma_f32_16x16x32_bf16(al0, bh[j], acc[0][j], 0, 0, 0);
            acc[1][j] = __builtin_amdgcn_mfma_f32_16x16x32_bf16(ah1, bh[j], acc[1][j], 0, 0, 0);
            acc[1][j] = __builtin_amdgcn_mfma_f32_16x16x32_bf16(ah1, bl[j], acc[1][j], 0, 0, 0);
            acc[1][j] = __builtin_amdgcn_mfma_f32_16x16x32_bf16(al1, bh[j], acc[1][j], 0, 0, 0);
        }
    }

    // C/D layout: col = lane&15, row = (lane>>4)*4 + reg
#pragma unroll
    for (int rt = 0; rt < 2; ++rt) {
#pragma unroll
        for (int j = 0; j < 4; ++j) {
            int cc = col0 + j * 16 + ln16;
            float bv = bias[cc];
#pragma unroll
            for (int r = 0; r < 4; ++r) {
                int rr = row0 + rt * 16 + q * 4 + r;
                if (rr >= N) continue;
                float v = selu_f(acc[rt][j][r] + bv);
                if (cc < 2) {
                    unsigned mk = masks[rr];
                    if (cc == 0) { if (mk & 2u) v = 0.f; else if (mk & 1u) v = 1.f; }
                    else         { if (mk & 8u) v = 1.f; else if (mk & 4u) v = 0.f; }
                }
                O16[(size_t)rr * M + cc] = __float2half(v);
            }
        }
    }
}

// ---------------- final layer (C=2): out = bfix(x + selu(g @ W5s + b5)) -----
__global__ __launch_bounds__(256) void final5_kernel(const unsigned short* __restrict__ ghi,
                                                     const unsigned short* __restrict__ glo,
                                                     const float* __restrict__ W5,
                                                     const float* __restrict__ b5,
                                                     const unsigned* __restrict__ masks,
                                                     const float* __restrict__ x,
                                                     float* __restrict__ out,
                                                     int N, int KA) {
    int wave = threadIdx.x >> 6, lane = threadIdx.x & 63;
    int n = blockIdx.x * 4 + wave;
    if (n >= N) return;
    float a0 = 0.f, a1 = 0.f;
    const unsigned short* gh = ghi + (size_t)n * KA;
    const unsigned short* gl = glo + (size_t)n * KA;
    for (int k = lane * 2; k < KA; k += 128) {
        ushort2 uh = *(const ushort2*)(gh + k);
        ushort2 ul = *(const ushort2*)(gl + k);
        float f0 = bf16_to_f(uh.x) + bf16_to_f(ul.x);
        float f1 = bf16_to_f(uh.y) + bf16_to_f(ul.y);
        float4 w = *(const float4*)(W5 + (size_t)k * 2);
        a0 += f0 * w.x + f1 * w.z;
        a1 += f0 * w.y + f1 * w.w;
    }
#pragma unroll
    for (int off = 32; off >= 1; off >>= 1) {
        a0 += __shfl_xor(a0, off);
        a1 += __shfl_xor(a1, off);
    }
    if (lane == 0) {
        unsigned mk = masks[n];
        float v0 = x[n * 10 + 0] + selu_f(a0 + b5[0]);
        float v1 = x[n * 10 + 1] + selu_f(a1 + b5[1]);
        if (mk & 2u) v0 = 0.f; else if (mk & 1u) v0 = 1.f;
        if (mk & 8u) v1 = 1.f; else if (mk & 4u) v1 = 0.f;
        out[n * 2 + 0] = v0;
        out[n * 2 + 1] = v1;
    }
}

// ---------------------------------------------------------------------------
extern "C" void kernel_launch(void* const* d_in, const int* in_sizes, int n_in,
                              void* d_out, int out_size, void* d_ws, size_t ws_size,
                              hipStream_t stream) {
    const float* x   = (const float*)d_in[0];
    const int*   ei  = (const int*)d_in[1];
    const float* cf  = (const float*)d_in[2];
    const float* cw[4] = {(const float*)d_in[3], (const float*)d_in[5],
                          (const float*)d_in[7], (const float*)d_in[9]};
    const float* cb[4] = {(const float*)d_in[4], (const float*)d_in[6],
                          (const float*)d_in[8], (const float*)d_in[10]};
    const float* gw[5], *gas[5], *gad[5], *gb[5];
    for (int i = 0; i < 5; ++i) {
        gw[i]  = (const float*)d_in[11 + 4 * i];
        gas[i] = (const float*)d_in[12 + 4 * i];
        gad[i] = (const float*)d_in[13 + 4 * i];
        gb[i]  = (const float*)d_in[14 + 4 * i];
    }
    const int N = in_sizes[0] / 10;        // 10000
    const int E = in_sizes[1] / 2;         // 160000
    const int EN = E + N;
    const int Np = 10048;                  // padded rows for GEMM A reads

    // ---- workspace carve-up ----
    char* base = (char*)d_ws;
    size_t off = 0;
    auto alloc = [&](size_t bytes) -> char* {
        char* p = base + off;
        off = (off + bytes + 255) & ~(size_t)255;
        return p;
    };
    float* c1    = (float*)alloc(16 * 4096 * 4);
    float* c2    = (float*)alloc(32 * 4096 * 4);
    float* c3    = (float*)alloc(64 * 4096 * 4);
    float* c4    = (float*)alloc(24 * 4096 * 4);
    float* gfeat = (float*)alloc(24 * 4);
    __half* hA16 = (__half*)alloc((size_t)N * 256 * 2);
    __half* hB16 = (__half*)alloc((size_t)N * 256 * 2);
    unsigned short* g_hi = (unsigned short*)alloc((size_t)Np * 2048 * 2);
    unsigned short* g_lo = (unsigned short*)alloc((size_t)Np * 2048 * 2);
    float* esed  = (float*)alloc((size_t)N * 32 * 4);
    float* zinv  = (float*)alloc((size_t)N * 16 * 4);
    __half* palpha = (__half*)alloc((size_t)EN * 16 * 2);
    float* wesed = (float*)alloc(256 * 32 * 4);
    float* wstack= (float*)alloc((size_t)2048 * 2 * 4);
    unsigned short* bt_hi = (unsigned short*)alloc((size_t)262144 * 2);
    unsigned short* bt_lo = (unsigned short*)alloc((size_t)262144 * 2);
    unsigned* masks = (unsigned*)alloc((size_t)N * 4);
    int* cnt    = (int*)alloc((size_t)N * 4);
    int* indptr = (int*)alloc((size_t)(N + 1) * 4);
    int* cursor = (int*)alloc((size_t)N * 4);
    int* col    = (int*)alloc((size_t)EN * 4);
    (void)ws_size; // ~98 MB

    // ---- CNN ----
    conv3x3_selu<<<(16 * 4096 + 255) / 256, 256, 0, stream>>>(cf, cw[0], cb[0], c1, 4, 16);
    conv3x3_selu<<<(32 * 4096 + 255) / 256, 256, 0, stream>>>(c1, cw[1], cb[1], c2, 16, 32);
    conv3x3_selu<<<(64 * 4096 + 255) / 256, 256, 0, stream>>>(c2, cw[2], cb[2], c3, 32, 64);
    conv3x3_selu<<<(24 * 4096 + 255) / 256, 256, 0, stream>>>(c3, cw[3], cb[3], c4, 64, 24);
    avgpool_c<<<24, 256, 0, stream>>>(c4, gfeat);

    // ---- h0 (padded to 48, fp16) + masks ----
    build_h0<<<(N + 255) / 256, 256, 0, stream>>>(x, gfeat, hA16, masks, N);

    // ---- CSR by dst (incl self loops) ----
    hipMemsetAsync(cnt, 0, (size_t)N * 4, stream);
    count_dst<<<(EN + 255) / 256, 256, 0, stream>>>(ei, cnt, E, N);
    exscan_single<<<1, 256, 0, stream>>>(cnt, indptr, N);
    copy_int<<<(N + 255) / 256, 256, 0, stream>>>(indptr, cursor, N);
    scatter_edges<<<(EN + 255) / 256, 256, 0, stream>>>(ei, cursor, col, E, N);

    // ---- GAT layers ----
    const int Ko[5] = {34, 64, 128, 256, 128};   // true input dims
    const int Kp[5] = {48, 64, 128, 256, 128};   // padded
    const int Hs[5] = {8, 16, 8, 8, 16};
    const int Cs[5] = {64, 128, 256, 128, 2};

    const __half* hin16 = hA16;
    __half* hout16[4]  = {hB16, hA16, hB16, hA16};

    for (int lyr = 0; lyr < 5; ++lyr) {
        int K = Ko[lyr], KP = Kp[lyr], H = Hs[lyr], C = Cs[lyr];
        int KA = H * KP;
        build_wesed<<<(KP * 2 * H + 255) / 256, 256, 0, stream>>>(gw[lyr], gas[lyr], gad[lyr],
                                                                  wesed, K, KP, H, C);
        esed_kernel<<<(N * 2 * H + 255) / 256, 256, 0, stream>>>(hin16, wesed, esed, N, KP, 2 * H);
        attn_kernel<<<(N * H + 255) / 256, 256, 0, stream>>>(esed, indptr, col, palpha, zinv, N, H);
        if (lyr == 0)
            gat_gather<8, 48, 10><<<(N + 9) / 10, 240, 0, stream>>>(hin16, palpha, zinv, indptr, col, g_hi, g_lo, N);
        else if (lyr == 1)
            gat_gather<16, 64, 8><<<(N + 7) / 8, 256, 0, stream>>>(hin16, palpha, zinv, indptr, col, g_hi, g_lo, N);
        else if (lyr == 2)
            gat_gather<8, 128, 4><<<(N + 3) / 4, 256, 0, stream>>>(hin16, palpha, zinv, indptr, col, g_hi, g_lo, N);
        else if (lyr == 3)
            gat_gather<8, 256, 2><<<(N + 1) / 2, 256, 0, stream>>>(hin16, palpha, zinv, indptr, col, g_hi, g_lo, N);
        else
            gat_gather<16, 128, 4><<<(N + 3) / 4, 256, 0, stream>>>(hin16, palpha, zinv, indptr, col, g_hi, g_lo, N);

        if (lyr < 4) {
            build_wtb<<<(C * KA + 255) / 256, 256, 0, stream>>>(gw[lyr], bt_hi, bt_lo, K, KP, H, C);
            int gblocks = (N + 31) / 32;
            if (C == 64)
                gemm32<1><<<gblocks, 64, 0, stream>>>(g_hi, g_lo, bt_hi, bt_lo, gb[lyr], masks, hout16[lyr], N, KA, C);
            else if (C == 128)
                gemm32<2><<<gblocks, 128, 0, stream>>>(g_hi, g_lo, bt_hi, bt_lo, gb[lyr], masks, hout16[lyr], N, KA, C);
            else
                gemm32<4><<<gblocks, 256, 0, stream>>>(g_hi, g_lo, bt_hi, bt_lo, gb[lyr], masks, hout16[lyr], N, KA, C);
            hin16 = hout16[lyr];
        } else {
            build_wstack<<<(KA * 2 + 255) / 256, 256, 0, stream>>>(gw[4], wstack, K, KP, H, 2);
            final5_kernel<<<(N + 3) / 4, 256, 0, stream>>>(g_hi, g_lo, wstack, gb[4], masks, x,
                                                           (float*)d_out, N, KA);
        }
    }
}

// Round 8
// 1060.754 us; speedup vs baseline: 1.4133x; 1.0446x over previous
//
#include <hip/hip_runtime.h>
#include <hip/hip_fp16.h>
#include <math.h>

// ---------------------------------------------------------------------------
// NetGlobGATFix. R8: split-K wave-granular MFMA GEMM.
//   - g stored fp16 single-plane (A bytes halved vs R7); in-register split
//     to bf16 hi/lo inside GEMM (exact for fp16).
//   - gemm_sk<SPLIT>: grid (N/16, M/64, SPLIT), 1 wave/block, 16x64 tile,
//     K-range per z-slice -> 2500 waves every layer (was 626-1250).
//     SPLIT==1: inline epilogue; SPLIT>1: fp32 partials + reduce_ep kernel.
// ---------------------------------------------------------------------------

#define DEVFN static __device__ __forceinline__

typedef __attribute__((ext_vector_type(8))) short short8;
typedef __attribute__((ext_vector_type(4))) float f32x4;

DEVFN float selu_f(float v) {
    const float scale = 1.0507009873554805f;
    const float alpha = 1.6732632423543772f;
    return v > 0.f ? scale * v : scale * alpha * (expf(v) - 1.f);
}

DEVFN float lrelu02(float v) { return v > 0.f ? v : 0.2f * v; }

// truncation split: hi = trunc_bf16(a); lo = trunc_bf16(a - hi)
DEVFN void split_bf16(float a, unsigned short& hi, unsigned short& lo) {
    unsigned u = __float_as_uint(a);
    hi = (unsigned short)(u >> 16);
    float hf = __uint_as_float(u & 0xFFFF0000u);
    float l = a - hf;
    lo = (unsigned short)(__float_as_uint(l) >> 16);
}

// ---------------- CNN ----------------
__global__ void conv3x3_selu(const float* __restrict__ in, const float* __restrict__ w,
                             const float* __restrict__ b, float* __restrict__ out,
                             int Cin, int Cout) {
    int t = blockIdx.x * blockDim.x + threadIdx.x;
    if (t >= Cout * 4096) return;
    int pix = t & 4095;
    int co  = t >> 12;
    int y = pix >> 6, x = pix & 63;
    float acc = b[co];
    for (int ci = 0; ci < Cin; ++ci) {
        const float* ip = in + ci * 4096;
        const float* wp = w + (co * Cin + ci) * 9;
#pragma unroll
        for (int ky = 0; ky < 3; ++ky) {
            int yy = y + ky - 1;
            if (yy < 0 || yy > 63) continue;
#pragma unroll
            for (int kx = 0; kx < 3; ++kx) {
                int xx = x + kx - 1;
                if (xx < 0 || xx > 63) continue;
                acc += ip[yy * 64 + xx] * wp[ky * 3 + kx];
            }
        }
    }
    out[t] = selu_f(acc);
}

__global__ void avgpool_c(const float* __restrict__ in, float* __restrict__ gfeat) {
    int c = blockIdx.x;            // 24 blocks
    int t = threadIdx.x;           // 256 threads
    float s = 0.f;
    for (int i = t; i < 4096; i += 256) s += in[c * 4096 + i];
#pragma unroll
    for (int off = 32; off >= 1; off >>= 1) s += __shfl_xor(s, off);
    __shared__ float red[4];
    int wave = t >> 6, lane = t & 63;
    if (lane == 0) red[wave] = s;
    __syncthreads();
    if (t == 0) gfeat[c] = (red[0] + red[1] + red[2] + red[3]) * (1.f / 4096.f);
}

// ---------------- node feature init (padded to 48 ch, fp16) + masks ---------
__global__ void build_h0(const float* __restrict__ x, const float* __restrict__ gfeat,
                         __half* __restrict__ h0f, unsigned* __restrict__ masks, int N) {
    int n = blockIdx.x * blockDim.x + threadIdx.x;
    if (n >= N) return;
    float x0 = x[n * 10 + 0], x1 = x[n * 10 + 1];
    unsigned mk = (x0 == 1.f ? 1u : 0u) | (x0 == 0.f ? 2u : 0u) |
                  (x1 == 0.f ? 4u : 0u) | (x1 == 1.f ? 8u : 0u);
    masks[n] = mk;
    __half* hq = h0f + (size_t)n * 48;
#pragma unroll
    for (int j = 0; j < 48; ++j) {
        float v = (j < 24) ? gfeat[j] : (j < 34 ? x[n * 10 + (j - 24)] : 0.f);
        hq[j] = __float2half(v);
    }
}

// ---------------- CSR build ----------------
__global__ void count_dst(const int* __restrict__ ei, int* __restrict__ cnt, int E, int N) {
    int t = blockIdx.x * blockDim.x + threadIdx.x;
    if (t >= E + N) return;
    int dst = (t < E) ? ei[E + t] : (t - E);
    atomicAdd(&cnt[dst], 1);
}

__global__ void exscan_single(const int* __restrict__ cnt, int* __restrict__ indptr, int n) {
    __shared__ int sdata[256];
    __shared__ int run_s;
    int tid = threadIdx.x;
    if (tid == 0) { run_s = 0; indptr[0] = 0; }
    __syncthreads();
    for (int base = 0; base < n; base += 256) {
        int i = base + tid;
        int v = (i < n) ? cnt[i] : 0;
        sdata[tid] = v;
        __syncthreads();
        for (int off = 1; off < 256; off <<= 1) {
            int tmp = (tid >= off) ? sdata[tid - off] : 0;
            __syncthreads();
            sdata[tid] += tmp;
            __syncthreads();
        }
        if (i < n) indptr[i + 1] = run_s + sdata[tid];
        __syncthreads();
        if (tid == 0) run_s += sdata[255];
        __syncthreads();
    }
}

__global__ void copy_int(const int* __restrict__ a, int* __restrict__ b, int n) {
    int t = blockIdx.x * blockDim.x + threadIdx.x;
    if (t < n) b[t] = a[t];
}

__global__ void scatter_edges(const int* __restrict__ ei, int* __restrict__ cursor,
                              int* __restrict__ col, int E, int N) {
    int t = blockIdx.x * blockDim.x + threadIdx.x;
    if (t >= E + N) return;
    int src, dst;
    if (t < E) { src = ei[t]; dst = ei[E + t]; }
    else       { src = dst = t - E; }
    int pos = atomicAdd(&cursor[dst], 1);
    col[pos] = src;
}

// ---------------- weight prep ----------------------------------------------
__global__ void build_wesed(const float* __restrict__ W, const float* __restrict__ as,
                            const float* __restrict__ ad, float* __restrict__ wesed,
                            int K, int Kp, int H, int C) {
    int H2 = 2 * H;
    int t = blockIdx.x * blockDim.x + threadIdx.x;
    if (t >= Kp * H2) return;
    int k = t / H2, o = t - k * H2;
    float s = 0.f;
    if (k < K) {
        int h = (o < H) ? o : o - H;
        const float* av = ((o < H) ? as : ad) + h * C;
        const float* wp = W + (size_t)k * (H * C) + h * C;
        for (int c = 0; c < C; ++c) s += wp[c] * av[c];
    }
    wesed[t] = s;
}

// Bt_hi/Bt_lo[m * KA + (h*Kp + k)] = split_bf16(W[k, h*C+m]), 0 pad for k>=K
__global__ void build_wtb(const float* __restrict__ W, unsigned short* __restrict__ bhi,
                          unsigned short* __restrict__ blo, int K, int Kp, int H, int C) {
    int KA = H * Kp;
    int t = blockIdx.x * blockDim.x + threadIdx.x;
    if (t >= C * KA) return;
    int ka = t % KA;
    int m  = t / KA;
    int h = ka / Kp, k = ka - h * Kp;
    float v = (k < K) ? W[(size_t)k * (H * C) + h * C + m] : 0.f;
    unsigned short hi, lo;
    split_bf16(v, hi, lo);
    bhi[t] = hi;
    blo[t] = lo;
}

// wstack[(h*Kp+k)*C + c] = W[k, h*C+c] (fp32; final layer C=2)
__global__ void build_wstack(const float* __restrict__ W, float* __restrict__ ws,
                             int K, int Kp, int H, int C) {
    int t = blockIdx.x * blockDim.x + threadIdx.x;
    if (t >= H * Kp * C) return;
    int c = t % C;
    int r = t / C;
    int h = r / Kp, k = r - h * Kp;
    ws[t] = (k < K) ? W[(size_t)k * (H * C) + h * C + c] : 0.f;
}

// ---------------- es/ed: esed[n, o] = hin16[n,:] @ wesed[:,o], o < 2H -------
__global__ void esed_kernel(const __half* __restrict__ hin, const float* __restrict__ wesed,
                            float* __restrict__ esed, int N, int Kp, int H2) {
    int t = blockIdx.x * blockDim.x + threadIdx.x;
    if (t >= N * H2) return;
    int n = t / H2, o = t - n * H2;
    const __half2* hp = (const __half2*)(hin + (size_t)n * Kp);
    float s = 0.f;
    for (int k2 = 0; k2 < Kp / 2; ++k2) {
        float2 f = __half22float2(hp[k2]);
        s += f.x * wesed[(2 * k2) * H2 + o] + f.y * wesed[(2 * k2 + 1) * H2 + o];
    }
    esed[t] = s;
}

// ---------------- attention: max pass + fp16 numerators + (1/H)/z -----------
__global__ void attn_kernel(const float* __restrict__ esed,
                            const int* __restrict__ indptr, const int* __restrict__ col,
                            __half* __restrict__ palpha, float* __restrict__ zinv,
                            int N, int H) {
    int t = blockIdx.x * blockDim.x + threadIdx.x;
    if (t >= N * H) return;
    int n = t / H, h = t - n * H;
    int H2 = 2 * H;
    float edv = esed[n * H2 + H + h];
    int beg = indptr[n], end = indptr[n + 1];
    float mv = -3.4e38f;
    for (int i = beg; i < end; ++i) {
        float e = lrelu02(esed[col[i] * H2 + h] + edv);
        mv = fmaxf(mv, e);
    }
    float z = 0.f;
    for (int i = beg; i < end; ++i) {
        float e = lrelu02(esed[col[i] * H2 + h] + edv);
        __half ph = __float2half(expf(e - mv));
        palpha[(size_t)i * H + h] = ph;
        z += __half2float(ph);
    }
    zinv[t] = (1.f / H) / (z + 1e-16f);
}

// ---------------- gather: g[n, h*KP+k] = zinv * Sum_e p * hin16[src, k] -----
template <int H, int KP, int NPB>
__global__ __launch_bounds__(NPB * KP / 2) void gat_gather(
        const __half* __restrict__ hinf, const __half* __restrict__ palpha,
        const float* __restrict__ zinv, const int* __restrict__ indptr,
        const int* __restrict__ col, __half* __restrict__ g, int N) {
    const int TPN = KP / 2;
    int sub = threadIdx.x / TPN;
    int j   = threadIdx.x % TPN;
    int n = blockIdx.x * NPB + sub;
    if (n >= N) return;
    int c0 = j * 2;
    float acc[H][2];
#pragma unroll
    for (int h = 0; h < H; ++h) { acc[h][0] = 0.f; acc[h][1] = 0.f; }
    int beg = indptr[n], end = indptr[n + 1];
    for (int i = beg; i < end; ++i) {
        int src = col[i];
        __half2 hv = *(const __half2*)(hinf + (size_t)src * KP + c0);
        float2 f = __half22float2(hv);
        const __half2* ap = (const __half2*)(palpha + (size_t)i * H);
#pragma unroll
        for (int h2 = 0; h2 < H / 2; ++h2) {
            float2 aa = __half22float2(ap[h2]);
            acc[2 * h2 + 0][0] += aa.x * f.x;
            acc[2 * h2 + 0][1] += aa.x * f.y;
            acc[2 * h2 + 1][0] += aa.y * f.x;
            acc[2 * h2 + 1][1] += aa.y * f.y;
        }
    }
    __half* gp = g + (size_t)n * (H * KP) + c0;
#pragma unroll
    for (int h = 0; h < H; ++h) {
        float zf = zinv[n * H + h];
        *(__half2*)(gp + h * KP) = __floats2half2_rn(acc[h][0] * zf, acc[h][1] * zf);
    }
}

// ---------------- split-K no-LDS MFMA GEMM ----------------------------------
// A fp16 [N x K], Bt hi/lo [M x K]. grid (N/16, M/64, SPLIT), 64 thr (1 wave),
// tile 16 x 64, k-range [z*K/SPLIT, (z+1)*K/SPLIT). K % (32*SPLIT) == 0.
// SPLIT==1: inline epilogue -> O16. SPLIT>1: fp32 partials P[z][n][m].
template <int SPLIT>
__global__ __launch_bounds__(64) void gemm_sk(const __half* __restrict__ A,
                                              const unsigned short* __restrict__ Bhi,
                                              const unsigned short* __restrict__ Blo,
                                              const float* __restrict__ bias,
                                              const unsigned* __restrict__ masks,
                                              float* __restrict__ P,
                                              __half* __restrict__ O16,
                                              int N, int K, int M) {
    int lane = threadIdx.x;
    int ln16 = lane & 15;
    int q    = lane >> 4;                 // 0..3 (k-octet)
    int row0 = blockIdx.x * 16;
    int col0 = blockIdx.y * 64;
    int kb   = (K / SPLIT) * blockIdx.z;
    int ke   = kb + K / SPLIT;

    const __half* ap = A + (size_t)(row0 + ln16) * K + q * 8;
    const unsigned short* bhp = Bhi + (size_t)(col0 + ln16) * K + q * 8;
    const unsigned short* blp = Blo + (size_t)(col0 + ln16) * K + q * 8;
    const size_t cstep = (size_t)16 * K;

    f32x4 acc[4];
#pragma unroll
    for (int j = 0; j < 4; ++j) acc[j] = (f32x4){0.f, 0.f, 0.f, 0.f};

#pragma unroll 2
    for (int kc = kb; kc < ke; kc += 32) {
        short8 araw = *(const short8*)(ap + kc);
        short8 bh[4], bl[4];
#pragma unroll
        for (int j = 0; j < 4; ++j) {
            bh[j] = *(const short8*)(bhp + (size_t)j * cstep + kc);
            bl[j] = *(const short8*)(blp + (size_t)j * cstep + kc);
        }
        // split A fp16 -> bf16 hi/lo (exact: fp16 fits in 2x bf16)
        short8 ah, al;
#pragma unroll
        for (int i = 0; i < 8; ++i) {
            __half_raw hr;
            hr.x = (unsigned short)araw[i];
            float f = __half2float(*(const __half*)&hr);
            unsigned uu = __float_as_uint(f);
            ah[i] = (short)(uu >> 16);
            float lf = f - __uint_as_float(uu & 0xFFFF0000u);
            al[i] = (short)(__float_as_uint(lf) >> 16);
        }
#pragma unroll
        for (int j = 0; j < 4; ++j) {
            acc[j] = __builtin_amdgcn_mfma_f32_16x16x32_bf16(ah, bh[j], acc[j], 0, 0, 0);
            acc[j] = __builtin_amdgcn_mfma_f32_16x16x32_bf16(ah, bl[j], acc[j], 0, 0, 0);
            acc[j] = __builtin_amdgcn_mfma_f32_16x16x32_bf16(al, bh[j], acc[j], 0, 0, 0);
        }
    }

    // C/D layout: col = lane&15, row = (lane>>4)*4 + reg
    if (SPLIT == 1) {
#pragma unroll
        for (int j = 0; j < 4; ++j) {
            int cc = col0 + j * 16 + ln16;
            float bv = bias[cc];
#pragma unroll
            for (int r = 0; r < 4; ++r) {
                int rr = row0 + q * 4 + r;
                float v = selu_f(acc[j][r] + bv);
                if (cc < 2) {
                    unsigned mk = masks[rr];
                    if (cc == 0) { if (mk & 2u) v = 0.f; else if (mk & 1u) v = 1.f; }
                    else         { if (mk & 8u) v = 1.f; else if (mk & 4u) v = 0.f; }
                }
                O16[(size_t)rr * M + cc] = __float2half(v);
            }
        }
    } else {
        float* Pz = P + (size_t)blockIdx.z * N * M;
#pragma unroll
        for (int j = 0; j < 4; ++j) {
            int cc = col0 + j * 16 + ln16;
#pragma unroll
            for (int r = 0; r < 4; ++r) {
                int rr = row0 + q * 4 + r;
                Pz[(size_t)rr * M + cc] = acc[j][r];
            }
        }
    }
}

// ---------------- reduce partials + bias/selu/boundary -> fp16 --------------
template <int SPLIT>
__global__ __launch_bounds__(256) void reduce_ep(const float* __restrict__ P,
                                                 const float* __restrict__ bias,
                                                 const unsigned* __restrict__ masks,
                                                 __half* __restrict__ O16,
                                                 int N, int M) {
    int t = blockIdx.x * 256 + threadIdx.x;
    if (t >= N * M) return;
    int n = t / M, c = t - n * M;
    float v = 0.f;
#pragma unroll
    for (int s = 0; s < SPLIT; ++s) v += P[(size_t)s * N * M + t];
    v = selu_f(v + bias[c]);
    if (c < 2) {
        unsigned mk = masks[n];
        if (c == 0) { if (mk & 2u) v = 0.f; else if (mk & 1u) v = 1.f; }
        else        { if (mk & 8u) v = 1.f; else if (mk & 4u) v = 0.f; }
    }
    O16[t] = __float2half(v);
}

// ---------------- final layer (C=2): out = bfix(x + selu(g @ W5s + b5)) -----
__global__ __launch_bounds__(256) void final5_kernel(const __half* __restrict__ g,
                                                     const float* __restrict__ W5,
                                                     const float* __restrict__ b5,
                                                     const unsigned* __restrict__ masks,
                                                     const float* __restrict__ x,
                                                     float* __restrict__ out,
                                                     int N, int KA) {
    int wave = threadIdx.x >> 6, lane = threadIdx.x & 63;
    int n = blockIdx.x * 4 + wave;
    if (n >= N) return;
    float a0 = 0.f, a1 = 0.f;
    const __half* gp = g + (size_t)n * KA;
    for (int k = lane * 2; k < KA; k += 128) {
        float2 f = __half22float2(*(const __half2*)(gp + k));
        float4 w = *(const float4*)(W5 + (size_t)k * 2);
        a0 += f.x * w.x + f.y * w.z;
        a1 += f.x * w.y + f.y * w.w;
    }
#pragma unroll
    for (int off = 32; off >= 1; off >>= 1) {
        a0 += __shfl_xor(a0, off);
        a1 += __shfl_xor(a1, off);
    }
    if (lane == 0) {
        unsigned mk = masks[n];
        float v0 = x[n * 10 + 0] + selu_f(a0 + b5[0]);
        float v1 = x[n * 10 + 1] + selu_f(a1 + b5[1]);
        if (mk & 2u) v0 = 0.f; else if (mk & 1u) v0 = 1.f;
        if (mk & 8u) v1 = 1.f; else if (mk & 4u) v1 = 0.f;
        out[n * 2 + 0] = v0;
        out[n * 2 + 1] = v1;
    }
}

// ---------------------------------------------------------------------------
extern "C" void kernel_launch(void* const* d_in, const int* in_sizes, int n_in,
                              void* d_out, int out_size, void* d_ws, size_t ws_size,
                              hipStream_t stream) {
    const float* x   = (const float*)d_in[0];
    const int*   ei  = (const int*)d_in[1];
    const float* cf  = (const float*)d_in[2];
    const float* cw[4] = {(const float*)d_in[3], (const float*)d_in[5],
                          (const float*)d_in[7], (const float*)d_in[9]};
    const float* cb[4] = {(const float*)d_in[4], (const float*)d_in[6],
                          (const float*)d_in[8], (const float*)d_in[10]};
    const float* gw[5], *gas[5], *gad[5], *gb[5];
    for (int i = 0; i < 5; ++i) {
        gw[i]  = (const float*)d_in[11 + 4 * i];
        gas[i] = (const float*)d_in[12 + 4 * i];
        gad[i] = (const float*)d_in[13 + 4 * i];
        gb[i]  = (const float*)d_in[14 + 4 * i];
    }
    const int N = in_sizes[0] / 10;        // 10000
    const int E = in_sizes[1] / 2;         // 160000
    const int EN = E + N;

    // ---- workspace carve-up ----
    char* base = (char*)d_ws;
    size_t off = 0;
    auto alloc = [&](size_t bytes) -> char* {
        char* p = base + off;
        off = (off + bytes + 255) & ~(size_t)255;
        return p;
    };
    float* c1    = (float*)alloc(16 * 4096 * 4);
    float* c2    = (float*)alloc(32 * 4096 * 4);
    float* c3    = (float*)alloc(64 * 4096 * 4);
    float* c4    = (float*)alloc(24 * 4096 * 4);
    float* gfeat = (float*)alloc(24 * 4);
    __half* hA16 = (__half*)alloc((size_t)N * 256 * 2);
    __half* hB16 = (__half*)alloc((size_t)N * 256 * 2);
    __half* g    = (__half*)alloc((size_t)N * 2048 * 2);
    float* P     = (float*)alloc((size_t)4 * N * 64 * 4 > (size_t)2 * N * 128 * 4
                                 ? (size_t)4 * N * 64 * 4 : (size_t)2 * N * 128 * 4); // 10.2 MB
    float* esed  = (float*)alloc((size_t)N * 32 * 4);
    float* zinv  = (float*)alloc((size_t)N * 16 * 4);
    __half* palpha = (__half*)alloc((size_t)EN * 16 * 2);
    float* wesed = (float*)alloc(256 * 32 * 4);
    float* wstack= (float*)alloc((size_t)2048 * 2 * 4);
    unsigned short* bt_hi = (unsigned short*)alloc((size_t)262144 * 2);
    unsigned short* bt_lo = (unsigned short*)alloc((size_t)262144 * 2);
    unsigned* masks = (unsigned*)alloc((size_t)N * 4);
    int* cnt    = (int*)alloc((size_t)N * 4);
    int* indptr = (int*)alloc((size_t)(N + 1) * 4);
    int* cursor = (int*)alloc((size_t)N * 4);
    int* col    = (int*)alloc((size_t)EN * 4);
    (void)ws_size; // ~80 MB

    // ---- CNN ----
    conv3x3_selu<<<(16 * 4096 + 255) / 256, 256, 0, stream>>>(cf, cw[0], cb[0], c1, 4, 16);
    conv3x3_selu<<<(32 * 4096 + 255) / 256, 256, 0, stream>>>(c1, cw[1], cb[1], c2, 16, 32);
    conv3x3_selu<<<(64 * 4096 + 255) / 256, 256, 0, stream>>>(c2, cw[2], cb[2], c3, 32, 64);
    conv3x3_selu<<<(24 * 4096 + 255) / 256, 256, 0, stream>>>(c3, cw[3], cb[3], c4, 64, 24);
    avgpool_c<<<24, 256, 0, stream>>>(c4, gfeat);

    // ---- h0 (padded to 48, fp16) + masks ----
    build_h0<<<(N + 255) / 256, 256, 0, stream>>>(x, gfeat, hA16, masks, N);

    // ---- CSR by dst (incl self loops) ----
    hipMemsetAsync(cnt, 0, (size_t)N * 4, stream);
    count_dst<<<(EN + 255) / 256, 256, 0, stream>>>(ei, cnt, E, N);
    exscan_single<<<1, 256, 0, stream>>>(cnt, indptr, N);
    copy_int<<<(N + 255) / 256, 256, 0, stream>>>(indptr, cursor, N);
    scatter_edges<<<(EN + 255) / 256, 256, 0, stream>>>(ei, cursor, col, E, N);

    // ---- GAT layers ----
    const int Ko[5] = {34, 64, 128, 256, 128};   // true input dims
    const int Kp[5] = {48, 64, 128, 256, 128};   // padded
    const int Hs[5] = {8, 16, 8, 8, 16};
    const int Cs[5] = {64, 128, 256, 128, 2};

    const __half* hin16 = hA16;
    __half* hout16[4]  = {hB16, hA16, hB16, hA16};

    for (int lyr = 0; lyr < 5; ++lyr) {
        int K = Ko[lyr], KP = Kp[lyr], H = Hs[lyr], C = Cs[lyr];
        int KA = H * KP;
        build_wesed<<<(KP * 2 * H + 255) / 256, 256, 0, stream>>>(gw[lyr], gas[lyr], gad[lyr],
                                                                  wesed, K, KP, H, C);
        esed_kernel<<<(N * 2 * H + 255) / 256, 256, 0, stream>>>(hin16, wesed, esed, N, KP, 2 * H);
        attn_kernel<<<(N * H + 255) / 256, 256, 0, stream>>>(esed, indptr, col, palpha, zinv, N, H);
        if (lyr == 0)
            gat_gather<8, 48, 10><<<(N + 9) / 10, 240, 0, stream>>>(hin16, palpha, zinv, indptr, col, g, N);
        else if (lyr == 1)
            gat_gather<16, 64, 8><<<(N + 7) / 8, 256, 0, stream>>>(hin16, palpha, zinv, indptr, col, g, N);
        else if (lyr == 2)
            gat_gather<8, 128, 4><<<(N + 3) / 4, 256, 0, stream>>>(hin16, palpha, zinv, indptr, col, g, N);
        else if (lyr == 3)
            gat_gather<8, 256, 2><<<(N + 1) / 2, 256, 0, stream>>>(hin16, palpha, zinv, indptr, col, g, N);
        else
            gat_gather<16, 128, 4><<<(N + 3) / 4, 256, 0, stream>>>(hin16, palpha, zinv, indptr, col, g, N);

        if (lyr < 4) {
            build_wtb<<<(C * KA + 255) / 256, 256, 0, stream>>>(gw[lyr], bt_hi, bt_lo, K, KP, H, C);
            if (lyr == 0) {           // KA=384, C=64: SPLIT=4 (2500 waves)
                dim3 gg(N / 16, C / 64, 4);
                gemm_sk<4><<<gg, 64, 0, stream>>>(g, bt_hi, bt_lo, gb[lyr], masks, P, hout16[lyr], N, KA, C);
                reduce_ep<4><<<(N * C + 255) / 256, 256, 0, stream>>>(P, gb[lyr], masks, hout16[lyr], N, C);
            } else if (lyr == 2) {    // KA=2048, C=256: SPLIT=1 (2500 waves)
                dim3 gg(N / 16, C / 64, 1);
                gemm_sk<1><<<gg, 64, 0, stream>>>(g, bt_hi, bt_lo, gb[lyr], masks, P, hout16[lyr], N, KA, C);
            } else {                  // KA=1024, C=128: SPLIT=2 (2500 waves)
                dim3 gg(N / 16, C / 64, 2);
                gemm_sk<2><<<gg, 64, 0, stream>>>(g, bt_hi, bt_lo, gb[lyr], masks, P, hout16[lyr], N, KA, C);
                reduce_ep<2><<<(N * C + 255) / 256, 256, 0, stream>>>(P, gb[lyr], masks, hout16[lyr], N, C);
            }
            hin16 = hout16[lyr];
        } else {
            build_wstack<<<(KA * 2 + 255) / 256, 256, 0, stream>>>(gw[4], wstack, K, KP, H, 2);
            final5_kernel<<<(N + 3) / 4, 256, 0, stream>>>(g, wstack, gb[4], masks, x,
                                                           (float*)d_out, N, KA);
        }
    }
}

// Round 9
// 973.133 us; speedup vs baseline: 1.5405x; 1.0900x over previous
//
#include <hip/hip_runtime.h>
#include <hip/hip_fp16.h>
#include <math.h>

// ---------------------------------------------------------------------------
// NetGlobGATFix. R9: multi-row-tile split-K MFMA GEMM.
//   gemm_mr<RT,SPLIT>: 1 wave/block, RT 16-row tiles x 64 cols; per 32-k
//   chunk: RT A-loads + 8 B-loads -> 12*RT MFMAs (B amortized over RT tiles).
//   SPLIT z-slices over K keep total waves ~2500. fp32 partials + reduce_ep.
// ---------------------------------------------------------------------------

#define DEVFN static __device__ __forceinline__

typedef __attribute__((ext_vector_type(8))) short short8;
typedef __attribute__((ext_vector_type(4))) float f32x4;

DEVFN float selu_f(float v) {
    const float scale = 1.0507009873554805f;
    const float alpha = 1.6732632423543772f;
    return v > 0.f ? scale * v : scale * alpha * (expf(v) - 1.f);
}

DEVFN float lrelu02(float v) { return v > 0.f ? v : 0.2f * v; }

// truncation split: hi = trunc_bf16(a); lo = trunc_bf16(a - hi)
DEVFN void split_bf16(float a, unsigned short& hi, unsigned short& lo) {
    unsigned u = __float_as_uint(a);
    hi = (unsigned short)(u >> 16);
    float hf = __uint_as_float(u & 0xFFFF0000u);
    float l = a - hf;
    lo = (unsigned short)(__float_as_uint(l) >> 16);
}

// ---------------- CNN ----------------
__global__ void conv3x3_selu(const float* __restrict__ in, const float* __restrict__ w,
                             const float* __restrict__ b, float* __restrict__ out,
                             int Cin, int Cout) {
    int t = blockIdx.x * blockDim.x + threadIdx.x;
    if (t >= Cout * 4096) return;
    int pix = t & 4095;
    int co  = t >> 12;
    int y = pix >> 6, x = pix & 63;
    float acc = b[co];
    for (int ci = 0; ci < Cin; ++ci) {
        const float* ip = in + ci * 4096;
        const float* wp = w + (co * Cin + ci) * 9;
#pragma unroll
        for (int ky = 0; ky < 3; ++ky) {
            int yy = y + ky - 1;
            if (yy < 0 || yy > 63) continue;
#pragma unroll
            for (int kx = 0; kx < 3; ++kx) {
                int xx = x + kx - 1;
                if (xx < 0 || xx > 63) continue;
                acc += ip[yy * 64 + xx] * wp[ky * 3 + kx];
            }
        }
    }
    out[t] = selu_f(acc);
}

__global__ void avgpool_c(const float* __restrict__ in, float* __restrict__ gfeat) {
    int c = blockIdx.x;            // 24 blocks
    int t = threadIdx.x;           // 256 threads
    float s = 0.f;
    for (int i = t; i < 4096; i += 256) s += in[c * 4096 + i];
#pragma unroll
    for (int off = 32; off >= 1; off >>= 1) s += __shfl_xor(s, off);
    __shared__ float red[4];
    int wave = t >> 6, lane = t & 63;
    if (lane == 0) red[wave] = s;
    __syncthreads();
    if (t == 0) gfeat[c] = (red[0] + red[1] + red[2] + red[3]) * (1.f / 4096.f);
}

// ---------------- node feature init (padded to 48 ch, fp16) + masks ---------
__global__ void build_h0(const float* __restrict__ x, const float* __restrict__ gfeat,
                         __half* __restrict__ h0f, unsigned* __restrict__ masks, int N) {
    int n = blockIdx.x * blockDim.x + threadIdx.x;
    if (n >= N) return;
    float x0 = x[n * 10 + 0], x1 = x[n * 10 + 1];
    unsigned mk = (x0 == 1.f ? 1u : 0u) | (x0 == 0.f ? 2u : 0u) |
                  (x1 == 0.f ? 4u : 0u) | (x1 == 1.f ? 8u : 0u);
    masks[n] = mk;
    __half* hq = h0f + (size_t)n * 48;
#pragma unroll
    for (int j = 0; j < 48; ++j) {
        float v = (j < 24) ? gfeat[j] : (j < 34 ? x[n * 10 + (j - 24)] : 0.f);
        hq[j] = __float2half(v);
    }
}

// ---------------- CSR build ----------------
__global__ void count_dst(const int* __restrict__ ei, int* __restrict__ cnt, int E, int N) {
    int t = blockIdx.x * blockDim.x + threadIdx.x;
    if (t >= E + N) return;
    int dst = (t < E) ? ei[E + t] : (t - E);
    atomicAdd(&cnt[dst], 1);
}

__global__ void exscan_single(const int* __restrict__ cnt, int* __restrict__ indptr, int n) {
    __shared__ int sdata[256];
    __shared__ int run_s;
    int tid = threadIdx.x;
    if (tid == 0) { run_s = 0; indptr[0] = 0; }
    __syncthreads();
    for (int base = 0; base < n; base += 256) {
        int i = base + tid;
        int v = (i < n) ? cnt[i] : 0;
        sdata[tid] = v;
        __syncthreads();
        for (int off = 1; off < 256; off <<= 1) {
            int tmp = (tid >= off) ? sdata[tid - off] : 0;
            __syncthreads();
            sdata[tid] += tmp;
            __syncthreads();
        }
        if (i < n) indptr[i + 1] = run_s + sdata[tid];
        __syncthreads();
        if (tid == 0) run_s += sdata[255];
        __syncthreads();
    }
}

__global__ void copy_int(const int* __restrict__ a, int* __restrict__ b, int n) {
    int t = blockIdx.x * blockDim.x + threadIdx.x;
    if (t < n) b[t] = a[t];
}

__global__ void scatter_edges(const int* __restrict__ ei, int* __restrict__ cursor,
                              int* __restrict__ col, int E, int N) {
    int t = blockIdx.x * blockDim.x + threadIdx.x;
    if (t >= E + N) return;
    int src, dst;
    if (t < E) { src = ei[t]; dst = ei[E + t]; }
    else       { src = dst = t - E; }
    int pos = atomicAdd(&cursor[dst], 1);
    col[pos] = src;
}

// ---------------- weight prep ----------------------------------------------
__global__ void build_wesed(const float* __restrict__ W, const float* __restrict__ as,
                            const float* __restrict__ ad, float* __restrict__ wesed,
                            int K, int Kp, int H, int C) {
    int H2 = 2 * H;
    int t = blockIdx.x * blockDim.x + threadIdx.x;
    if (t >= Kp * H2) return;
    int k = t / H2, o = t - k * H2;
    float s = 0.f;
    if (k < K) {
        int h = (o < H) ? o : o - H;
        const float* av = ((o < H) ? as : ad) + h * C;
        const float* wp = W + (size_t)k * (H * C) + h * C;
        for (int c = 0; c < C; ++c) s += wp[c] * av[c];
    }
    wesed[t] = s;
}

// Bt_hi/Bt_lo[m * KA + (h*Kp + k)] = split_bf16(W[k, h*C+m]), 0 pad for k>=K
__global__ void build_wtb(const float* __restrict__ W, unsigned short* __restrict__ bhi,
                          unsigned short* __restrict__ blo, int K, int Kp, int H, int C) {
    int KA = H * Kp;
    int t = blockIdx.x * blockDim.x + threadIdx.x;
    if (t >= C * KA) return;
    int ka = t % KA;
    int m  = t / KA;
    int h = ka / Kp, k = ka - h * Kp;
    float v = (k < K) ? W[(size_t)k * (H * C) + h * C + m] : 0.f;
    unsigned short hi, lo;
    split_bf16(v, hi, lo);
    bhi[t] = hi;
    blo[t] = lo;
}

// wstack[(h*Kp+k)*C + c] = W[k, h*C+c] (fp32; final layer C=2)
__global__ void build_wstack(const float* __restrict__ W, float* __restrict__ ws,
                             int K, int Kp, int H, int C) {
    int t = blockIdx.x * blockDim.x + threadIdx.x;
    if (t >= H * Kp * C) return;
    int c = t % C;
    int r = t / C;
    int h = r / Kp, k = r - h * Kp;
    ws[t] = (k < K) ? W[(size_t)k * (H * C) + h * C + c] : 0.f;
}

// ---------------- es/ed: esed[n, o] = hin16[n,:] @ wesed[:,o], o < 2H -------
__global__ void esed_kernel(const __half* __restrict__ hin, const float* __restrict__ wesed,
                            float* __restrict__ esed, int N, int Kp, int H2) {
    int t = blockIdx.x * blockDim.x + threadIdx.x;
    if (t >= N * H2) return;
    int n = t / H2, o = t - n * H2;
    const __half2* hp = (const __half2*)(hin + (size_t)n * Kp);
    float s = 0.f;
    for (int k2 = 0; k2 < Kp / 2; ++k2) {
        float2 f = __half22float2(hp[k2]);
        s += f.x * wesed[(2 * k2) * H2 + o] + f.y * wesed[(2 * k2 + 1) * H2 + o];
    }
    esed[t] = s;
}

// ---------------- attention: max pass + fp16 numerators + (1/H)/z -----------
__global__ void attn_kernel(const float* __restrict__ esed,
                            const int* __restrict__ indptr, const int* __restrict__ col,
                            __half* __restrict__ palpha, float* __restrict__ zinv,
                            int N, int H) {
    int t = blockIdx.x * blockDim.x + threadIdx.x;
    if (t >= N * H) return;
    int n = t / H, h = t - n * H;
    int H2 = 2 * H;
    float edv = esed[n * H2 + H + h];
    int beg = indptr[n], end = indptr[n + 1];
    float mv = -3.4e38f;
    for (int i = beg; i < end; ++i) {
        float e = lrelu02(esed[col[i] * H2 + h] + edv);
        mv = fmaxf(mv, e);
    }
    float z = 0.f;
    for (int i = beg; i < end; ++i) {
        float e = lrelu02(esed[col[i] * H2 + h] + edv);
        __half ph = __float2half(expf(e - mv));
        palpha[(size_t)i * H + h] = ph;
        z += __half2float(ph);
    }
    zinv[t] = (1.f / H) / (z + 1e-16f);
}

// ---------------- gather: g[n, h*KP+k] = zinv * Sum_e p * hin16[src, k] -----
template <int H, int KP, int NPB>
__global__ __launch_bounds__(NPB * KP / 2) void gat_gather(
        const __half* __restrict__ hinf, const __half* __restrict__ palpha,
        const float* __restrict__ zinv, const int* __restrict__ indptr,
        const int* __restrict__ col, __half* __restrict__ g, int N) {
    const int TPN = KP / 2;
    int sub = threadIdx.x / TPN;
    int j   = threadIdx.x % TPN;
    int n = blockIdx.x * NPB + sub;
    if (n >= N) return;
    int c0 = j * 2;
    float acc[H][2];
#pragma unroll
    for (int h = 0; h < H; ++h) { acc[h][0] = 0.f; acc[h][1] = 0.f; }
    int beg = indptr[n], end = indptr[n + 1];
    for (int i = beg; i < end; ++i) {
        int src = col[i];
        __half2 hv = *(const __half2*)(hinf + (size_t)src * KP + c0);
        float2 f = __half22float2(hv);
        const __half2* ap = (const __half2*)(palpha + (size_t)i * H);
#pragma unroll
        for (int h2 = 0; h2 < H / 2; ++h2) {
            float2 aa = __half22float2(ap[h2]);
            acc[2 * h2 + 0][0] += aa.x * f.x;
            acc[2 * h2 + 0][1] += aa.x * f.y;
            acc[2 * h2 + 1][0] += aa.y * f.x;
            acc[2 * h2 + 1][1] += aa.y * f.y;
        }
    }
    __half* gp = g + (size_t)n * (H * KP) + c0;
#pragma unroll
    for (int h = 0; h < H; ++h) {
        float zf = zinv[n * H + h];
        *(__half2*)(gp + h * KP) = __floats2half2_rn(acc[h][0] * zf, acc[h][1] * zf);
    }
}

// ---------------- multi-row-tile split-K MFMA GEMM --------------------------
// A fp16 [N x K], Bt hi/lo [M x K]. grid (ceil(N/(16*RT)), M/64, SPLIT),
// 64 thr (1 wave); wave: RT 16-row tiles x 64 cols; k-range per z-slice.
// K % (32*SPLIT) == 0. SPLIT==1: inline epilogue; else fp32 partials P.
template <int RT, int SPLIT>
__global__ __launch_bounds__(64) void gemm_mr(const __half* __restrict__ A,
                                              const unsigned short* __restrict__ Bhi,
                                              const unsigned short* __restrict__ Blo,
                                              const float* __restrict__ bias,
                                              const unsigned* __restrict__ masks,
                                              float* __restrict__ P,
                                              __half* __restrict__ O16,
                                              int N, int K, int M) {
    int lane = threadIdx.x;
    int ln16 = lane & 15;
    int q    = lane >> 4;                 // 0..3 (k-octet)
    int row0 = blockIdx.x * (16 * RT);
    int col0 = blockIdx.y * 64;
    int kb   = (K / SPLIT) * blockIdx.z;
    int ke   = kb + K / SPLIT;

    const __half* ap = A + (size_t)(row0 + ln16) * K + q * 8;
    const unsigned short* bhp = Bhi + (size_t)(col0 + ln16) * K + q * 8;
    const unsigned short* blp = Blo + (size_t)(col0 + ln16) * K + q * 8;
    const size_t cstep = (size_t)16 * K;

    f32x4 acc[RT][4];
#pragma unroll
    for (int rt = 0; rt < RT; ++rt)
#pragma unroll
        for (int j = 0; j < 4; ++j) acc[rt][j] = (f32x4){0.f, 0.f, 0.f, 0.f};

#pragma unroll 2
    for (int kc = kb; kc < ke; kc += 32) {
        short8 bh[4], bl[4];
#pragma unroll
        for (int j = 0; j < 4; ++j) {
            bh[j] = *(const short8*)(bhp + (size_t)j * cstep + kc);
            bl[j] = *(const short8*)(blp + (size_t)j * cstep + kc);
        }
        short8 araw[RT];
#pragma unroll
        for (int rt = 0; rt < RT; ++rt)
            araw[rt] = *(const short8*)(ap + (size_t)rt * cstep + kc);
        // split A fp16 -> bf16 hi/lo (exact: fp16 fits in 2x bf16)
        short8 ah[RT], al[RT];
#pragma unroll
        for (int rt = 0; rt < RT; ++rt) {
#pragma unroll
            for (int i = 0; i < 8; ++i) {
                __half_raw hr;
                hr.x = (unsigned short)araw[rt][i];
                float f = __half2float(*(const __half*)&hr);
                unsigned uu = __float_as_uint(f);
                ah[rt][i] = (short)(uu >> 16);
                float lf = f - __uint_as_float(uu & 0xFFFF0000u);
                al[rt][i] = (short)(__float_as_uint(lf) >> 16);
            }
        }
#pragma unroll
        for (int rt = 0; rt < RT; ++rt) {
#pragma unroll
            for (int j = 0; j < 4; ++j) {
                acc[rt][j] = __builtin_amdgcn_mfma_f32_16x16x32_bf16(ah[rt], bh[j], acc[rt][j], 0, 0, 0);
                acc[rt][j] = __builtin_amdgcn_mfma_f32_16x16x32_bf16(ah[rt], bl[j], acc[rt][j], 0, 0, 0);
                acc[rt][j] = __builtin_amdgcn_mfma_f32_16x16x32_bf16(al[rt], bh[j], acc[rt][j], 0, 0, 0);
            }
        }
    }

    // C/D layout: col = lane&15, row = (lane>>4)*4 + reg
    if (SPLIT == 1) {
#pragma unroll
        for (int rt = 0; rt < RT; ++rt) {
#pragma unroll
            for (int j = 0; j < 4; ++j) {
                int cc = col0 + j * 16 + ln16;
                float bv = bias[cc];
#pragma unroll
                for (int r = 0; r < 4; ++r) {
                    int rr = row0 + rt * 16 + q * 4 + r;
                    if (rr >= N) continue;
                    float v = selu_f(acc[rt][j][r] + bv);
                    if (cc < 2) {
                        unsigned mk = masks[rr];
                        if (cc == 0) { if (mk & 2u) v = 0.f; else if (mk & 1u) v = 1.f; }
                        else         { if (mk & 8u) v = 1.f; else if (mk & 4u) v = 0.f; }
                    }
                    O16[(size_t)rr * M + cc] = __float2half(v);
                }
            }
        }
    } else {
        float* Pz = P + (size_t)blockIdx.z * N * M;
#pragma unroll
        for (int rt = 0; rt < RT; ++rt) {
#pragma unroll
            for (int j = 0; j < 4; ++j) {
                int cc = col0 + j * 16 + ln16;
#pragma unroll
                for (int r = 0; r < 4; ++r) {
                    int rr = row0 + rt * 16 + q * 4 + r;
                    if (rr >= N) continue;
                    Pz[(size_t)rr * M + cc] = acc[rt][j][r];
                }
            }
        }
    }
}

// ---------------- reduce partials + bias/selu/boundary -> fp16 --------------
template <int SPLIT>
__global__ __launch_bounds__(256) void reduce_ep(const float* __restrict__ P,
                                                 const float* __restrict__ bias,
                                                 const unsigned* __restrict__ masks,
                                                 __half* __restrict__ O16,
                                                 int N, int M) {
    int t = blockIdx.x * 256 + threadIdx.x;
    if (t >= N * M) return;
    int n = t / M, c = t - n * M;
    float v = 0.f;
#pragma unroll
    for (int s = 0; s < SPLIT; ++s) v += P[(size_t)s * N * M + t];
    v = selu_f(v + bias[c]);
    if (c < 2) {
        unsigned mk = masks[n];
        if (c == 0) { if (mk & 2u) v = 0.f; else if (mk & 1u) v = 1.f; }
        else        { if (mk & 8u) v = 1.f; else if (mk & 4u) v = 0.f; }
    }
    O16[t] = __float2half(v);
}

// ---------------- final layer (C=2): out = bfix(x + selu(g @ W5s + b5)) -----
__global__ __launch_bounds__(256) void final5_kernel(const __half* __restrict__ g,
                                                     const float* __restrict__ W5,
                                                     const float* __restrict__ b5,
                                                     const unsigned* __restrict__ masks,
                                                     const float* __restrict__ x,
                                                     float* __restrict__ out,
                                                     int N, int KA) {
    int wave = threadIdx.x >> 6, lane = threadIdx.x & 63;
    int n = blockIdx.x * 4 + wave;
    if (n >= N) return;
    float a0 = 0.f, a1 = 0.f;
    const __half* gp = g + (size_t)n * KA;
    for (int k = lane * 2; k < KA; k += 128) {
        float2 f = __half22float2(*(const __half2*)(gp + k));
        float4 w = *(const float4*)(W5 + (size_t)k * 2);
        a0 += f.x * w.x + f.y * w.z;
        a1 += f.x * w.y + f.y * w.w;
    }
#pragma unroll
    for (int off = 32; off >= 1; off >>= 1) {
        a0 += __shfl_xor(a0, off);
        a1 += __shfl_xor(a1, off);
    }
    if (lane == 0) {
        unsigned mk = masks[n];
        float v0 = x[n * 10 + 0] + selu_f(a0 + b5[0]);
        float v1 = x[n * 10 + 1] + selu_f(a1 + b5[1]);
        if (mk & 2u) v0 = 0.f; else if (mk & 1u) v0 = 1.f;
        if (mk & 8u) v1 = 1.f; else if (mk & 4u) v1 = 0.f;
        out[n * 2 + 0] = v0;
        out[n * 2 + 1] = v1;
    }
}

// ---------------------------------------------------------------------------
extern "C" void kernel_launch(void* const* d_in, const int* in_sizes, int n_in,
                              void* d_out, int out_size, void* d_ws, size_t ws_size,
                              hipStream_t stream) {
    const float* x   = (const float*)d_in[0];
    const int*   ei  = (const int*)d_in[1];
    const float* cf  = (const float*)d_in[2];
    const float* cw[4] = {(const float*)d_in[3], (const float*)d_in[5],
                          (const float*)d_in[7], (const float*)d_in[9]};
    const float* cb[4] = {(const float*)d_in[4], (const float*)d_in[6],
                          (const float*)d_in[8], (const float*)d_in[10]};
    const float* gw[5], *gas[5], *gad[5], *gb[5];
    for (int i = 0; i < 5; ++i) {
        gw[i]  = (const float*)d_in[11 + 4 * i];
        gas[i] = (const float*)d_in[12 + 4 * i];
        gad[i] = (const float*)d_in[13 + 4 * i];
        gb[i]  = (const float*)d_in[14 + 4 * i];
    }
    const int N = in_sizes[0] / 10;        // 10000
    const int E = in_sizes[1] / 2;         // 160000
    const int EN = E + N;

    // ---- workspace carve-up ----
    char* base = (char*)d_ws;
    size_t off = 0;
    auto alloc = [&](size_t bytes) -> char* {
        char* p = base + off;
        off = (off + bytes + 255) & ~(size_t)255;
        return p;
    };
    float* c1    = (float*)alloc(16 * 4096 * 4);
    float* c2    = (float*)alloc(32 * 4096 * 4);
    float* c3    = (float*)alloc(64 * 4096 * 4);
    float* c4    = (float*)alloc(24 * 4096 * 4);
    float* gfeat = (float*)alloc(24 * 4);
    __half* hA16 = (__half*)alloc((size_t)N * 256 * 2);
    __half* hB16 = (__half*)alloc((size_t)N * 256 * 2);
    __half* g    = (__half*)alloc((size_t)N * 2048 * 2);
    float* P     = (float*)alloc((size_t)4 * N * 256 * 4);   // 41 MB max partials
    float* esed  = (float*)alloc((size_t)N * 32 * 4);
    float* zinv  = (float*)alloc((size_t)N * 16 * 4);
    __half* palpha = (__half*)alloc((size_t)EN * 16 * 2);
    float* wesed = (float*)alloc(256 * 32 * 4);
    float* wstack= (float*)alloc((size_t)2048 * 2 * 4);
    unsigned short* bt_hi = (unsigned short*)alloc((size_t)262144 * 2);
    unsigned short* bt_lo = (unsigned short*)alloc((size_t)262144 * 2);
    unsigned* masks = (unsigned*)alloc((size_t)N * 4);
    int* cnt    = (int*)alloc((size_t)N * 4);
    int* indptr = (int*)alloc((size_t)(N + 1) * 4);
    int* cursor = (int*)alloc((size_t)N * 4);
    int* col    = (int*)alloc((size_t)EN * 4);
    (void)ws_size; // ~110 MB

    // ---- CNN ----
    conv3x3_selu<<<(16 * 4096 + 255) / 256, 256, 0, stream>>>(cf, cw[0], cb[0], c1, 4, 16);
    conv3x3_selu<<<(32 * 4096 + 255) / 256, 256, 0, stream>>>(c1, cw[1], cb[1], c2, 16, 32);
    conv3x3_selu<<<(64 * 4096 + 255) / 256, 256, 0, stream>>>(c2, cw[2], cb[2], c3, 32, 64);
    conv3x3_selu<<<(24 * 4096 + 255) / 256, 256, 0, stream>>>(c3, cw[3], cb[3], c4, 64, 24);
    avgpool_c<<<24, 256, 0, stream>>>(c4, gfeat);

    // ---- h0 (padded to 48, fp16) + masks ----
    build_h0<<<(N + 255) / 256, 256, 0, stream>>>(x, gfeat, hA16, masks, N);

    // ---- CSR by dst (incl self loops) ----
    hipMemsetAsync(cnt, 0, (size_t)N * 4, stream);
    count_dst<<<(EN + 255) / 256, 256, 0, stream>>>(ei, cnt, E, N);
    exscan_single<<<1, 256, 0, stream>>>(cnt, indptr, N);
    copy_int<<<(N + 255) / 256, 256, 0, stream>>>(indptr, cursor, N);
    scatter_edges<<<(EN + 255) / 256, 256, 0, stream>>>(ei, cursor, col, E, N);

    // ---- GAT layers ----
    const int Ko[5] = {34, 64, 128, 256, 128};   // true input dims
    const int Kp[5] = {48, 64, 128, 256, 128};   // padded
    const int Hs[5] = {8, 16, 8, 8, 16};
    const int Cs[5] = {64, 128, 256, 128, 2};

    const __half* hin16 = hA16;
    __half* hout16[4]  = {hB16, hA16, hB16, hA16};

    for (int lyr = 0; lyr < 5; ++lyr) {
        int K = Ko[lyr], KP = Kp[lyr], H = Hs[lyr], C = Cs[lyr];
        int KA = H * KP;
        build_wesed<<<(KP * 2 * H + 255) / 256, 256, 0, stream>>>(gw[lyr], gas[lyr], gad[lyr],
                                                                  wesed, K, KP, H, C);
        esed_kernel<<<(N * 2 * H + 255) / 256, 256, 0, stream>>>(hin16, wesed, esed, N, KP, 2 * H);
        attn_kernel<<<(N * H + 255) / 256, 256, 0, stream>>>(esed, indptr, col, palpha, zinv, N, H);
        if (lyr == 0)
            gat_gather<8, 48, 10><<<(N + 9) / 10, 240, 0, stream>>>(hin16, palpha, zinv, indptr, col, g, N);
        else if (lyr == 1)
            gat_gather<16, 64, 8><<<(N + 7) / 8, 256, 0, stream>>>(hin16, palpha, zinv, indptr, col, g, N);
        else if (lyr == 2)
            gat_gather<8, 128, 4><<<(N + 3) / 4, 256, 0, stream>>>(hin16, palpha, zinv, indptr, col, g, N);
        else if (lyr == 3)
            gat_gather<8, 256, 2><<<(N + 1) / 2, 256, 0, stream>>>(hin16, palpha, zinv, indptr, col, g, N);
        else
            gat_gather<16, 128, 4><<<(N + 3) / 4, 256, 0, stream>>>(hin16, palpha, zinv, indptr, col, g, N);

        if (lyr < 4) {
            build_wtb<<<(C * KA + 255) / 256, 256, 0, stream>>>(gw[lyr], bt_hi, bt_lo, K, KP, H, C);
            if (lyr == 0) {            // KA=384, C=64: RT=2, SPLIT=4 -> 1252 waves
                dim3 gg((N + 31) / 32, C / 64, 4);
                gemm_mr<2, 4><<<gg, 64, 0, stream>>>(g, bt_hi, bt_lo, gb[lyr], masks, P, hout16[lyr], N, KA, C);
                reduce_ep<4><<<(N * C + 255) / 256, 256, 0, stream>>>(P, gb[lyr], masks, hout16[lyr], N, C);
            } else if (lyr == 2) {     // KA=2048, C=256: RT=4, SPLIT=4 -> 2512 waves
                dim3 gg((N + 63) / 64, C / 64, 4);
                gemm_mr<4, 4><<<gg, 64, 0, stream>>>(g, bt_hi, bt_lo, gb[lyr], masks, P, hout16[lyr], N, KA, C);
                reduce_ep<4><<<(N * C + 255) / 256, 256, 0, stream>>>(P, gb[lyr], masks, hout16[lyr], N, C);
            } else {                   // KA=1024, C=128: RT=2, SPLIT=4 -> 2504 waves
                dim3 gg((N + 31) / 32, C / 64, 4);
                gemm_mr<2, 4><<<gg, 64, 0, stream>>>(g, bt_hi, bt_lo, gb[lyr], masks, P, hout16[lyr], N, KA, C);
                reduce_ep<4><<<(N * C + 255) / 256, 256, 0, stream>>>(P, gb[lyr], masks, hout16[lyr], N, C);
            }
            hin16 = hout16[lyr];
        } else {
            build_wstack<<<(KA * 2 + 255) / 256, 256, 0, stream>>>(gw[4], wstack, K, KP, H, 2);
            final5_kernel<<<(N + 3) / 4, 256, 0, stream>>>(g, wstack, gb[4], masks, x,
                                                           (float*)d_out, N, KA);
        }
    }
}

// Round 10
// 874.477 us; speedup vs baseline: 1.7143x; 1.1128x over previous
//
#include <hip/hip_runtime.h>
#include <hip/hip_fp16.h>
#include <math.h>

// ---------------------------------------------------------------------------
// NetGlobGATFix. R10: branch-free unrolled CNN on zero-padded 66x66 layout.
//   - conv3x3_pad<CIN>: template CIN (full unroll), V=4 vertical outputs per
//     thread, no bounds branches (padded input), scalar weight loads.
//   - GAT pipeline unchanged from R9 (gemm_mr split-K MFMA etc).
// ---------------------------------------------------------------------------

#define DEVFN static __device__ __forceinline__

typedef __attribute__((ext_vector_type(8))) short short8;
typedef __attribute__((ext_vector_type(4))) float f32x4;

DEVFN float selu_f(float v) {
    const float scale = 1.0507009873554805f;
    const float alpha = 1.6732632423543772f;
    return v > 0.f ? scale * v : scale * alpha * (expf(v) - 1.f);
}

DEVFN float lrelu02(float v) { return v > 0.f ? v : 0.2f * v; }

// truncation split: hi = trunc_bf16(a); lo = trunc_bf16(a - hi)
DEVFN void split_bf16(float a, unsigned short& hi, unsigned short& lo) {
    unsigned u = __float_as_uint(a);
    hi = (unsigned short)(u >> 16);
    float hf = __uint_as_float(u & 0xFFFF0000u);
    float l = a - hf;
    lo = (unsigned short)(__float_as_uint(l) >> 16);
}

// ---------------- CNN (padded 66x66 layout) ----------------
#define PST 66
#define PSZ (66 * 66)

__global__ void pad_input(const float* __restrict__ cf, float* __restrict__ out) {
    int t = blockIdx.x * blockDim.x + threadIdx.x;
    if (t >= 4 * 4096) return;
    int c = t >> 12, pix = t & 4095;
    int y = pix >> 6, x = pix & 63;
    out[c * PSZ + (y + 1) * PST + (x + 1)] = cf[t];
}

// in [CIN][66*66] padded, w [Cout][CIN][9], out [Cout][66*66] padded.
// grid (4, Cout), 256 thr; thread: col x, rows y0..y0+3.
template <int CIN>
__global__ __launch_bounds__(256) void conv3x3_pad(const float* __restrict__ in,
                                                   const float* __restrict__ w,
                                                   const float* __restrict__ b,
                                                   float* __restrict__ out) {
    int x  = threadIdx.x & 63;
    int yg = threadIdx.x >> 6;
    int y0 = blockIdx.x * 16 + yg * 4;
    int co = blockIdx.y;
    float bv = b[co];
    float acc[4] = {bv, bv, bv, bv};
    const float* wp = w + (size_t)co * CIN * 9;
#pragma unroll 4
    for (int ci = 0; ci < CIN; ++ci) {
        const float* ip = in + ci * PSZ + y0 * PST + x;
        float wr[9];
#pragma unroll
        for (int j = 0; j < 9; ++j) wr[j] = wp[ci * 9 + j];
        float r[6][3];
#pragma unroll
        for (int rr = 0; rr < 6; ++rr) {
            r[rr][0] = ip[rr * PST + 0];
            r[rr][1] = ip[rr * PST + 1];
            r[rr][2] = ip[rr * PST + 2];
        }
#pragma unroll
        for (int v = 0; v < 4; ++v)
#pragma unroll
            for (int ky = 0; ky < 3; ++ky)
#pragma unroll
                for (int kx = 0; kx < 3; ++kx)
                    acc[v] += wr[ky * 3 + kx] * r[v + ky][kx];
    }
#pragma unroll
    for (int v = 0; v < 4; ++v)
        out[(size_t)co * PSZ + (y0 + v + 1) * PST + (x + 1)] = selu_f(acc[v]);
}

__global__ void avgpool_c(const float* __restrict__ in, float* __restrict__ gfeat) {
    int c = blockIdx.x;            // 24 blocks
    int t = threadIdx.x;           // 256 threads
    float s = 0.f;
    for (int i = t; i < 4096; i += 256) {
        int y = i >> 6, x = i & 63;
        s += in[c * PSZ + (y + 1) * PST + (x + 1)];
    }
#pragma unroll
    for (int off = 32; off >= 1; off >>= 1) s += __shfl_xor(s, off);
    __shared__ float red[4];
    int wave = t >> 6, lane = t & 63;
    if (lane == 0) red[wave] = s;
    __syncthreads();
    if (t == 0) gfeat[c] = (red[0] + red[1] + red[2] + red[3]) * (1.f / 4096.f);
}

// ---------------- node feature init (padded to 48 ch, fp16) + masks ---------
__global__ void build_h0(const float* __restrict__ x, const float* __restrict__ gfeat,
                         __half* __restrict__ h0f, unsigned* __restrict__ masks, int N) {
    int n = blockIdx.x * blockDim.x + threadIdx.x;
    if (n >= N) return;
    float x0 = x[n * 10 + 0], x1 = x[n * 10 + 1];
    unsigned mk = (x0 == 1.f ? 1u : 0u) | (x0 == 0.f ? 2u : 0u) |
                  (x1 == 0.f ? 4u : 0u) | (x1 == 1.f ? 8u : 0u);
    masks[n] = mk;
    __half* hq = h0f + (size_t)n * 48;
#pragma unroll
    for (int j = 0; j < 48; ++j) {
        float v = (j < 24) ? gfeat[j] : (j < 34 ? x[n * 10 + (j - 24)] : 0.f);
        hq[j] = __float2half(v);
    }
}

// ---------------- CSR build ----------------
__global__ void count_dst(const int* __restrict__ ei, int* __restrict__ cnt, int E, int N) {
    int t = blockIdx.x * blockDim.x + threadIdx.x;
    if (t >= E + N) return;
    int dst = (t < E) ? ei[E + t] : (t - E);
    atomicAdd(&cnt[dst], 1);
}

__global__ void exscan_single(const int* __restrict__ cnt, int* __restrict__ indptr, int n) {
    __shared__ int sdata[256];
    __shared__ int run_s;
    int tid = threadIdx.x;
    if (tid == 0) { run_s = 0; indptr[0] = 0; }
    __syncthreads();
    for (int base = 0; base < n; base += 256) {
        int i = base + tid;
        int v = (i < n) ? cnt[i] : 0;
        sdata[tid] = v;
        __syncthreads();
        for (int off = 1; off < 256; off <<= 1) {
            int tmp = (tid >= off) ? sdata[tid - off] : 0;
            __syncthreads();
            sdata[tid] += tmp;
            __syncthreads();
        }
        if (i < n) indptr[i + 1] = run_s + sdata[tid];
        __syncthreads();
        if (tid == 0) run_s += sdata[255];
        __syncthreads();
    }
}

__global__ void copy_int(const int* __restrict__ a, int* __restrict__ b, int n) {
    int t = blockIdx.x * blockDim.x + threadIdx.x;
    if (t < n) b[t] = a[t];
}

__global__ void scatter_edges(const int* __restrict__ ei, int* __restrict__ cursor,
                              int* __restrict__ col, int E, int N) {
    int t = blockIdx.x * blockDim.x + threadIdx.x;
    if (t >= E + N) return;
    int src, dst;
    if (t < E) { src = ei[t]; dst = ei[E + t]; }
    else       { src = dst = t - E; }
    int pos = atomicAdd(&cursor[dst], 1);
    col[pos] = src;
}

// ---------------- weight prep ----------------------------------------------
__global__ void build_wesed(const float* __restrict__ W, const float* __restrict__ as,
                            const float* __restrict__ ad, float* __restrict__ wesed,
                            int K, int Kp, int H, int C) {
    int H2 = 2 * H;
    int t = blockIdx.x * blockDim.x + threadIdx.x;
    if (t >= Kp * H2) return;
    int k = t / H2, o = t - k * H2;
    float s = 0.f;
    if (k < K) {
        int h = (o < H) ? o : o - H;
        const float* av = ((o < H) ? as : ad) + h * C;
        const float* wp = W + (size_t)k * (H * C) + h * C;
        for (int c = 0; c < C; ++c) s += wp[c] * av[c];
    }
    wesed[t] = s;
}

// Bt_hi/Bt_lo[m * KA + (h*Kp + k)] = split_bf16(W[k, h*C+m]), 0 pad for k>=K
__global__ void build_wtb(const float* __restrict__ W, unsigned short* __restrict__ bhi,
                          unsigned short* __restrict__ blo, int K, int Kp, int H, int C) {
    int KA = H * Kp;
    int t = blockIdx.x * blockDim.x + threadIdx.x;
    if (t >= C * KA) return;
    int ka = t % KA;
    int m  = t / KA;
    int h = ka / Kp, k = ka - h * Kp;
    float v = (k < K) ? W[(size_t)k * (H * C) + h * C + m] : 0.f;
    unsigned short hi, lo;
    split_bf16(v, hi, lo);
    bhi[t] = hi;
    blo[t] = lo;
}

// wstack[(h*Kp+k)*C + c] = W[k, h*C+c] (fp32; final layer C=2)
__global__ void build_wstack(const float* __restrict__ W, float* __restrict__ ws,
                             int K, int Kp, int H, int C) {
    int t = blockIdx.x * blockDim.x + threadIdx.x;
    if (t >= H * Kp * C) return;
    int c = t % C;
    int r = t / C;
    int h = r / Kp, k = r - h * Kp;
    ws[t] = (k < K) ? W[(size_t)k * (H * C) + h * C + c] : 0.f;
}

// ---------------- es/ed: esed[n, o] = hin16[n,:] @ wesed[:,o], o < 2H -------
__global__ void esed_kernel(const __half* __restrict__ hin, const float* __restrict__ wesed,
                            float* __restrict__ esed, int N, int Kp, int H2) {
    int t = blockIdx.x * blockDim.x + threadIdx.x;
    if (t >= N * H2) return;
    int n = t / H2, o = t - n * H2;
    const __half2* hp = (const __half2*)(hin + (size_t)n * Kp);
    float s = 0.f;
    for (int k2 = 0; k2 < Kp / 2; ++k2) {
        float2 f = __half22float2(hp[k2]);
        s += f.x * wesed[(2 * k2) * H2 + o] + f.y * wesed[(2 * k2 + 1) * H2 + o];
    }
    esed[t] = s;
}

// ---------------- attention: max pass + fp16 numerators + (1/H)/z -----------
__global__ void attn_kernel(const float* __restrict__ esed,
                            const int* __restrict__ indptr, const int* __restrict__ col,
                            __half* __restrict__ palpha, float* __restrict__ zinv,
                            int N, int H) {
    int t = blockIdx.x * blockDim.x + threadIdx.x;
    if (t >= N * H) return;
    int n = t / H, h = t - n * H;
    int H2 = 2 * H;
    float edv = esed[n * H2 + H + h];
    int beg = indptr[n], end = indptr[n + 1];
    float mv = -3.4e38f;
    for (int i = beg; i < end; ++i) {
        float e = lrelu02(esed[col[i] * H2 + h] + edv);
        mv = fmaxf(mv, e);
    }
    float z = 0.f;
    for (int i = beg; i < end; ++i) {
        float e = lrelu02(esed[col[i] * H2 + h] + edv);
        __half ph = __float2half(expf(e - mv));
        palpha[(size_t)i * H + h] = ph;
        z += __half2float(ph);
    }
    zinv[t] = (1.f / H) / (z + 1e-16f);
}

// ---------------- gather: g[n, h*KP+k] = zinv * Sum_e p * hin16[src, k] -----
template <int H, int KP, int NPB>
__global__ __launch_bounds__(NPB * KP / 2) void gat_gather(
        const __half* __restrict__ hinf, const __half* __restrict__ palpha,
        const float* __restrict__ zinv, const int* __restrict__ indptr,
        const int* __restrict__ col, __half* __restrict__ g, int N) {
    const int TPN = KP / 2;
    int sub = threadIdx.x / TPN;
    int j   = threadIdx.x % TPN;
    int n = blockIdx.x * NPB + sub;
    if (n >= N) return;
    int c0 = j * 2;
    float acc[H][2];
#pragma unroll
    for (int h = 0; h < H; ++h) { acc[h][0] = 0.f; acc[h][1] = 0.f; }
    int beg = indptr[n], end = indptr[n + 1];
    for (int i = beg; i < end; ++i) {
        int src = col[i];
        __half2 hv = *(const __half2*)(hinf + (size_t)src * KP + c0);
        float2 f = __half22float2(hv);
        const __half2* ap = (const __half2*)(palpha + (size_t)i * H);
#pragma unroll
        for (int h2 = 0; h2 < H / 2; ++h2) {
            float2 aa = __half22float2(ap[h2]);
            acc[2 * h2 + 0][0] += aa.x * f.x;
            acc[2 * h2 + 0][1] += aa.x * f.y;
            acc[2 * h2 + 1][0] += aa.y * f.x;
            acc[2 * h2 + 1][1] += aa.y * f.y;
        }
    }
    __half* gp = g + (size_t)n * (H * KP) + c0;
#pragma unroll
    for (int h = 0; h < H; ++h) {
        float zf = zinv[n * H + h];
        *(__half2*)(gp + h * KP) = __floats2half2_rn(acc[h][0] * zf, acc[h][1] * zf);
    }
}

// ---------------- multi-row-tile split-K MFMA GEMM --------------------------
// A fp16 [N x K], Bt hi/lo [M x K]. grid (ceil(N/(16*RT)), M/64, SPLIT),
// 64 thr (1 wave); wave: RT 16-row tiles x 64 cols; k-range per z-slice.
// K % (32*SPLIT) == 0. SPLIT==1: inline epilogue; else fp32 partials P.
template <int RT, int SPLIT>
__global__ __launch_bounds__(64) void gemm_mr(const __half* __restrict__ A,
                                              const unsigned short* __restrict__ Bhi,
                                              const unsigned short* __restrict__ Blo,
                                              const float* __restrict__ bias,
                                              const unsigned* __restrict__ masks,
                                              float* __restrict__ P,
                                              __half* __restrict__ O16,
                                              int N, int K, int M) {
    int lane = threadIdx.x;
    int ln16 = lane & 15;
    int q    = lane >> 4;                 // 0..3 (k-octet)
    int row0 = blockIdx.x * (16 * RT);
    int col0 = blockIdx.y * 64;
    int kb   = (K / SPLIT) * blockIdx.z;
    int ke   = kb + K / SPLIT;

    const __half* ap = A + (size_t)(row0 + ln16) * K + q * 8;
    const unsigned short* bhp = Bhi + (size_t)(col0 + ln16) * K + q * 8;
    const unsigned short* blp = Blo + (size_t)(col0 + ln16) * K + q * 8;
    const size_t cstep = (size_t)16 * K;

    f32x4 acc[RT][4];
#pragma unroll
    for (int rt = 0; rt < RT; ++rt)
#pragma unroll
        for (int j = 0; j < 4; ++j) acc[rt][j] = (f32x4){0.f, 0.f, 0.f, 0.f};

#pragma unroll 2
    for (int kc = kb; kc < ke; kc += 32) {
        short8 bh[4], bl[4];
#pragma unroll
        for (int j = 0; j < 4; ++j) {
            bh[j] = *(const short8*)(bhp + (size_t)j * cstep + kc);
            bl[j] = *(const short8*)(blp + (size_t)j * cstep + kc);
        }
        short8 araw[RT];
#pragma unroll
        for (int rt = 0; rt < RT; ++rt)
            araw[rt] = *(const short8*)(ap + (size_t)rt * cstep + kc);
        // split A fp16 -> bf16 hi/lo (exact: fp16 fits in 2x bf16)
        short8 ah[RT], al[RT];
#pragma unroll
        for (int rt = 0; rt < RT; ++rt) {
#pragma unroll
            for (int i = 0; i < 8; ++i) {
                __half_raw hr;
                hr.x = (unsigned short)araw[rt][i];
                float f = __half2float(*(const __half*)&hr);
                unsigned uu = __float_as_uint(f);
                ah[rt][i] = (short)(uu >> 16);
                float lf = f - __uint_as_float(uu & 0xFFFF0000u);
                al[rt][i] = (short)(__float_as_uint(lf) >> 16);
            }
        }
#pragma unroll
        for (int rt = 0; rt < RT; ++rt) {
#pragma unroll
            for (int j = 0; j < 4; ++j) {
                acc[rt][j] = __builtin_amdgcn_mfma_f32_16x16x32_bf16(ah[rt], bh[j], acc[rt][j], 0, 0, 0);
                acc[rt][j] = __builtin_amdgcn_mfma_f32_16x16x32_bf16(ah[rt], bl[j], acc[rt][j], 0, 0, 0);
                acc[rt][j] = __builtin_amdgcn_mfma_f32_16x16x32_bf16(al[rt], bh[j], acc[rt][j], 0, 0, 0);
            }
        }
    }

    // C/D layout: col = lane&15, row = (lane>>4)*4 + reg
    if (SPLIT == 1) {
#pragma unroll
        for (int rt = 0; rt < RT; ++rt) {
#pragma unroll
            for (int j = 0; j < 4; ++j) {
                int cc = col0 + j * 16 + ln16;
                float bv = bias[cc];
#pragma unroll
                for (int r = 0; r < 4; ++r) {
                    int rr = row0 + rt * 16 + q * 4 + r;
                    if (rr >= N) continue;
                    float v = selu_f(acc[rt][j][r] + bv);
                    if (cc < 2) {
                        unsigned mk = masks[rr];
                        if (cc == 0) { if (mk & 2u) v = 0.f; else if (mk & 1u) v = 1.f; }
                        else         { if (mk & 8u) v = 1.f; else if (mk & 4u) v = 0.f; }
                    }
                    O16[(size_t)rr * M + cc] = __float2half(v);
                }
            }
        }
    } else {
        float* Pz = P + (size_t)blockIdx.z * N * M;
#pragma unroll
        for (int rt = 0; rt < RT; ++rt) {
#pragma unroll
            for (int j = 0; j < 4; ++j) {
                int cc = col0 + j * 16 + ln16;
#pragma unroll
                for (int r = 0; r < 4; ++r) {
                    int rr = row0 + rt * 16 + q * 4 + r;
                    if (rr >= N) continue;
                    Pz[(size_t)rr * M + cc] = acc[rt][j][r];
                }
            }
        }
    }
}

// ---------------- reduce partials + bias/selu/boundary -> fp16 --------------
template <int SPLIT>
__global__ __launch_bounds__(256) void reduce_ep(const float* __restrict__ P,
                                                 const float* __restrict__ bias,
                                                 const unsigned* __restrict__ masks,
                                                 __half* __restrict__ O16,
                                                 int N, int M) {
    int t = blockIdx.x * 256 + threadIdx.x;
    if (t >= N * M) return;
    int n = t / M, c = t - n * M;
    float v = 0.f;
#pragma unroll
    for (int s = 0; s < SPLIT; ++s) v += P[(size_t)s * N * M + t];
    v = selu_f(v + bias[c]);
    if (c < 2) {
        unsigned mk = masks[n];
        if (c == 0) { if (mk & 2u) v = 0.f; else if (mk & 1u) v = 1.f; }
        else        { if (mk & 8u) v = 1.f; else if (mk & 4u) v = 0.f; }
    }
    O16[t] = __float2half(v);
}

// ---------------- final layer (C=2): out = bfix(x + selu(g @ W5s + b5)) -----
__global__ __launch_bounds__(256) void final5_kernel(const __half* __restrict__ g,
                                                     const float* __restrict__ W5,
                                                     const float* __restrict__ b5,
                                                     const unsigned* __restrict__ masks,
                                                     const float* __restrict__ x,
                                                     float* __restrict__ out,
                                                     int N, int KA) {
    int wave = threadIdx.x >> 6, lane = threadIdx.x & 63;
    int n = blockIdx.x * 4 + wave;
    if (n >= N) return;
    float a0 = 0.f, a1 = 0.f;
    const __half* gp = g + (size_t)n * KA;
    for (int k = lane * 2; k < KA; k += 128) {
        float2 f = __half22float2(*(const __half2*)(gp + k));
        float4 w = *(const float4*)(W5 + (size_t)k * 2);
        a0 += f.x * w.x + f.y * w.z;
        a1 += f.x * w.y + f.y * w.w;
    }
#pragma unroll
    for (int off = 32; off >= 1; off >>= 1) {
        a0 += __shfl_xor(a0, off);
        a1 += __shfl_xor(a1, off);
    }
    if (lane == 0) {
        unsigned mk = masks[n];
        float v0 = x[n * 10 + 0] + selu_f(a0 + b5[0]);
        float v1 = x[n * 10 + 1] + selu_f(a1 + b5[1]);
        if (mk & 2u) v0 = 0.f; else if (mk & 1u) v0 = 1.f;
        if (mk & 8u) v1 = 1.f; else if (mk & 4u) v1 = 0.f;
        out[n * 2 + 0] = v0;
        out[n * 2 + 1] = v1;
    }
}

// ---------------------------------------------------------------------------
extern "C" void kernel_launch(void* const* d_in, const int* in_sizes, int n_in,
                              void* d_out, int out_size, void* d_ws, size_t ws_size,
                              hipStream_t stream) {
    const float* x   = (const float*)d_in[0];
    const int*   ei  = (const int*)d_in[1];
    const float* cf  = (const float*)d_in[2];
    const float* cw[4] = {(const float*)d_in[3], (const float*)d_in[5],
                          (const float*)d_in[7], (const float*)d_in[9]};
    const float* cb[4] = {(const float*)d_in[4], (const float*)d_in[6],
                          (const float*)d_in[8], (const float*)d_in[10]};
    const float* gw[5], *gas[5], *gad[5], *gb[5];
    for (int i = 0; i < 5; ++i) {
        gw[i]  = (const float*)d_in[11 + 4 * i];
        gas[i] = (const float*)d_in[12 + 4 * i];
        gad[i] = (const float*)d_in[13 + 4 * i];
        gb[i]  = (const float*)d_in[14 + 4 * i];
    }
    const int N = in_sizes[0] / 10;        // 10000
    const int E = in_sizes[1] / 2;         // 160000
    const int EN = E + N;

    // ---- workspace carve-up ----
    char* base = (char*)d_ws;
    size_t off = 0;
    auto alloc = [&](size_t bytes) -> char* {
        char* p = base + off;
        off = (off + bytes + 255) & ~(size_t)255;
        return p;
    };
    // padded conv buffers, contiguous for one memset (140 ch * 4356 * 4B)
    float* cfp   = (float*)alloc((size_t)4 * PSZ * 4);
    float* c1p   = (float*)alloc((size_t)16 * PSZ * 4);
    float* c2p   = (float*)alloc((size_t)32 * PSZ * 4);
    float* c3p   = (float*)alloc((size_t)64 * PSZ * 4);
    float* c4p   = (float*)alloc((size_t)24 * PSZ * 4);
    float* gfeat = (float*)alloc(24 * 4);
    __half* hA16 = (__half*)alloc((size_t)N * 256 * 2);
    __half* hB16 = (__half*)alloc((size_t)N * 256 * 2);
    __half* g    = (__half*)alloc((size_t)N * 2048 * 2);
    float* P     = (float*)alloc((size_t)4 * N * 256 * 4);   // 41 MB max partials
    float* esed  = (float*)alloc((size_t)N * 32 * 4);
    float* zinv  = (float*)alloc((size_t)N * 16 * 4);
    __half* palpha = (__half*)alloc((size_t)EN * 16 * 2);
    float* wesed = (float*)alloc(256 * 32 * 4);
    float* wstack= (float*)alloc((size_t)2048 * 2 * 4);
    unsigned short* bt_hi = (unsigned short*)alloc((size_t)262144 * 2);
    unsigned short* bt_lo = (unsigned short*)alloc((size_t)262144 * 2);
    unsigned* masks = (unsigned*)alloc((size_t)N * 4);
    int* cnt    = (int*)alloc((size_t)N * 4);
    int* indptr = (int*)alloc((size_t)(N + 1) * 4);
    int* cursor = (int*)alloc((size_t)N * 4);
    int* col    = (int*)alloc((size_t)EN * 4);
    (void)ws_size; // ~112 MB

    // ---- CNN (padded layout; single memset zeroes all borders) ----
    hipMemsetAsync(cfp, 0, (size_t)140 * PSZ * 4, stream);
    pad_input<<<(4 * 4096 + 255) / 256, 256, 0, stream>>>(cf, cfp);
    conv3x3_pad<4><<<dim3(4, 16), 256, 0, stream>>>(cfp, cw[0], cb[0], c1p);
    conv3x3_pad<16><<<dim3(4, 32), 256, 0, stream>>>(c1p, cw[1], cb[1], c2p);
    conv3x3_pad<32><<<dim3(4, 64), 256, 0, stream>>>(c2p, cw[2], cb[2], c3p);
    conv3x3_pad<64><<<dim3(4, 24), 256, 0, stream>>>(c3p, cw[3], cb[3], c4p);
    avgpool_c<<<24, 256, 0, stream>>>(c4p, gfeat);

    // ---- h0 (padded to 48, fp16) + masks ----
    build_h0<<<(N + 255) / 256, 256, 0, stream>>>(x, gfeat, hA16, masks, N);

    // ---- CSR by dst (incl self loops) ----
    hipMemsetAsync(cnt, 0, (size_t)N * 4, stream);
    count_dst<<<(EN + 255) / 256, 256, 0, stream>>>(ei, cnt, E, N);
    exscan_single<<<1, 256, 0, stream>>>(cnt, indptr, N);
    copy_int<<<(N + 255) / 256, 256, 0, stream>>>(indptr, cursor, N);
    scatter_edges<<<(EN + 255) / 256, 256, 0, stream>>>(ei, cursor, col, E, N);

    // ---- GAT layers ----
    const int Ko[5] = {34, 64, 128, 256, 128};   // true input dims
    const int Kp[5] = {48, 64, 128, 256, 128};   // padded
    const int Hs[5] = {8, 16, 8, 8, 16};
    const int Cs[5] = {64, 128, 256, 128, 2};

    const __half* hin16 = hA16;
    __half* hout16[4]  = {hB16, hA16, hB16, hA16};

    for (int lyr = 0; lyr < 5; ++lyr) {
        int K = Ko[lyr], KP = Kp[lyr], H = Hs[lyr], C = Cs[lyr];
        int KA = H * KP;
        build_wesed<<<(KP * 2 * H + 255) / 256, 256, 0, stream>>>(gw[lyr], gas[lyr], gad[lyr],
                                                                  wesed, K, KP, H, C);
        esed_kernel<<<(N * 2 * H + 255) / 256, 256, 0, stream>>>(hin16, wesed, esed, N, KP, 2 * H);
        attn_kernel<<<(N * H + 255) / 256, 256, 0, stream>>>(esed, indptr, col, palpha, zinv, N, H);
        if (lyr == 0)
            gat_gather<8, 48, 10><<<(N + 9) / 10, 240, 0, stream>>>(hin16, palpha, zinv, indptr, col, g, N);
        else if (lyr == 1)
            gat_gather<16, 64, 8><<<(N + 7) / 8, 256, 0, stream>>>(hin16, palpha, zinv, indptr, col, g, N);
        else if (lyr == 2)
            gat_gather<8, 128, 4><<<(N + 3) / 4, 256, 0, stream>>>(hin16, palpha, zinv, indptr, col, g, N);
        else if (lyr == 3)
            gat_gather<8, 256, 2><<<(N + 1) / 2, 256, 0, stream>>>(hin16, palpha, zinv, indptr, col, g, N);
        else
            gat_gather<16, 128, 4><<<(N + 3) / 4, 256, 0, stream>>>(hin16, palpha, zinv, indptr, col, g, N);

        if (lyr < 4) {
            build_wtb<<<(C * KA + 255) / 256, 256, 0, stream>>>(gw[lyr], bt_hi, bt_lo, K, KP, H, C);
            if (lyr == 0) {            // KA=384, C=64: RT=2, SPLIT=4 -> 1252 waves
                dim3 gg((N + 31) / 32, C / 64, 4);
                gemm_mr<2, 4><<<gg, 64, 0, stream>>>(g, bt_hi, bt_lo, gb[lyr], masks, P, hout16[lyr], N, KA, C);
                reduce_ep<4><<<(N * C + 255) / 256, 256, 0, stream>>>(P, gb[lyr], masks, hout16[lyr], N, C);
            } else if (lyr == 2) {     // KA=2048, C=256: RT=4, SPLIT=4 -> 2512 waves
                dim3 gg((N + 63) / 64, C / 64, 4);
                gemm_mr<4, 4><<<gg, 64, 0, stream>>>(g, bt_hi, bt_lo, gb[lyr], masks, P, hout16[lyr], N, KA, C);
                reduce_ep<4><<<(N * C + 255) / 256, 256, 0, stream>>>(P, gb[lyr], masks, hout16[lyr], N, C);
            } else {                   // KA=1024, C=128: RT=2, SPLIT=4 -> 2504 waves
                dim3 gg((N + 31) / 32, C / 64, 4);
                gemm_mr<2, 4><<<gg, 64, 0, stream>>>(g, bt_hi, bt_lo, gb[lyr], masks, P, hout16[lyr], N, KA, C);
                reduce_ep<4><<<(N * C + 255) / 256, 256, 0, stream>>>(P, gb[lyr], masks, hout16[lyr], N, C);
            }
            hin16 = hout16[lyr];
        } else {
            build_wstack<<<(KA * 2 + 255) / 256, 256, 0, stream>>>(gw[4], wstack, K, KP, H, 2);
            final5_kernel<<<(N + 3) / 4, 256, 0, stream>>>(g, wstack, gb[4], masks, x,
                                                           (float*)d_out, N, KA);
        }
    }
}